// Round 11
// baseline (269.599 us; speedup 1.0000x reference)
//
#include <hip/hip_runtime.h>
#include <hip/hip_bf16.h>
#include <cstdint>
#include <cstddef>

#define HIDDEN   2048
#define NH       16
#define NKV      4
#define HD       128
#define SEQ      2048
#define BATCH    2
#define NTOK     (BATCH*SEQ)      // 4096
#define QKV_LD   3072             // Q(2048) | K(512) | V(512)
#define KOFF     2048
#define VOFF     2560
#define SM_SCALE 0.08838834764831845f   // 1/sqrt(128)
#define LOG2E    1.4426950408889634f

typedef __attribute__((ext_vector_type(8)))  short bf16x8;
typedef __attribute__((ext_vector_type(4)))  float f32x4v;
typedef __attribute__((ext_vector_type(16))) float f32x16;
typedef unsigned short ushort_t;

__device__ __forceinline__ unsigned short f2bf(float f) {
  return __builtin_bit_cast(unsigned short, __float2bfloat16(f));
}
__device__ __forceinline__ float bf2f(ushort_t u) {
  return __builtin_bit_cast(float, (unsigned)u << 16);
}
__device__ __forceinline__ unsigned pack2(float a, float b) {
  return (unsigned)f2bf(a) | ((unsigned)f2bf(b) << 16);
}

// async global->LDS, 16B/lane; LDS dest lane-linear, swizzle realized on the GLOBAL src.
__device__ __forceinline__ void gload16(const void* g, void* l) {
  __builtin_amdgcn_global_load_lds(
      (const __attribute__((address_space(1))) unsigned int*)g,
      (__attribute__((address_space(3))) unsigned int*)l, 16, 0, 0);
}

// ---------------- conversion kernels ----------------
__global__ __launch_bounds__(256) void conv_f2b(
    const float* __restrict__ in, ushort_t* __restrict__ out, int n8)
{
  const int i = blockIdx.x*256 + threadIdx.x;
  if (i >= n8) return;
  const float4 a = ((const float4*)in)[2*i];
  const float4 b = ((const float4*)in)[2*i + 1];
  uint4 r;
  r.x = pack2(a.x, a.y); r.y = pack2(a.z, a.w);
  r.z = pack2(b.x, b.y); r.w = pack2(b.z, b.w);
  ((uint4*)out)[i] = r;
}

// W[K][N] fp32 -> Wt[N][K] bf16
__global__ __launch_bounds__(256) void transpose_f2b(
    const float* __restrict__ W, ushort_t* __restrict__ Wt, int K, int N)
{
  __shared__ float tile[32][33];
  const int n0 = blockIdx.x*32, k0 = blockIdx.y*32;
  const int tx = threadIdx.x & 31, ty = threadIdx.x >> 5;
  #pragma unroll
  for (int i = 0; i < 4; ++i)
    tile[ty*4 + i][tx] = W[(size_t)(k0 + ty*4 + i)*N + n0 + tx];
  __syncthreads();
  #pragma unroll
  for (int i = 0; i < 4; ++i) {
    const int nl = ty*4 + i;
    Wt[(size_t)(n0 + nl)*K + k0 + tx] = f2bf(tile[tx][nl]);
  }
}

// ---------------- bf16 MFMA GEMM (m97 structure) + T1 XCD-chunked block swizzle ----
// Requires gridDim.x*gridDim.y % 8 == 0 (768 and 512 here).
template<bool B16OUT>
__global__ __launch_bounds__(256) void bt_gemm(
    const ushort_t* __restrict__ A, const ushort_t* __restrict__ Bt,
    void* __restrict__ Cv, int ldc)
{
  __shared__ ushort_t As[128*64];
  __shared__ ushort_t Bs[128*64];
  const int t = threadIdx.x, lane = t & 63, w = t >> 6;
  // T1: HW dispatch id d round-robins XCDs; give XCD x a contiguous tile chunk.
  const int gx = gridDim.x;
  const int d  = blockIdx.y*gx + blockIdx.x;
  const int qc = (gx*gridDim.y) >> 3;
  const int sid = (d & 7)*qc + (d >> 3);
  const int bm = (sid / gx)*128, bn = (sid % gx)*128;
  const int wr = w >> 1, wc = w & 1;
  const int lr = lane & 15, lg = lane >> 4;

  f32x4v acc[4][4];
  #pragma unroll
  for (int fm = 0; fm < 4; ++fm)
    #pragma unroll
    for (int fn = 0; fn < 4; ++fn)
      #pragma unroll
      for (int r = 0; r < 4; ++r) acc[fm][fn][r] = 0.f;

  const char* Ab = (const char*)A;
  const char* Bb = (const char*)Bt;
  char* asb = (char*)As;
  char* bsb = (char*)Bs;

  for (int kt = 0; kt < HIDDEN*2; kt += 128) {
    __syncthreads();
    #pragma unroll
    for (int u = 0; u < 4; ++u) {
      const int idx = u*256 + t;
      const int row = idx >> 3;
      const int kb  = (idx & 7) * 16;
      const int skb = kb ^ ((row & 7) << 4);
      gload16(Ab + (size_t)(bm + row)*4096 + kt + skb, asb + idx*16);
      gload16(Bb + (size_t)(bn + row)*4096 + kt + skb, bsb + idx*16);
    }
    __syncthreads();
    #pragma unroll
    for (int kc = 0; kc < 2; ++kc) {
      bf16x8 af[4], bfr[4];
      #pragma unroll
      for (int f = 0; f < 4; ++f) {
        const int rm = wr*64 + f*16 + lr;
        af[f]  = *(const bf16x8*)(asb + rm*128 + ((kc*64 + lg*16) ^ ((rm & 7) << 4)));
        const int rn = wc*64 + f*16 + lr;
        bfr[f] = *(const bf16x8*)(bsb + rn*128 + ((kc*64 + lg*16) ^ ((rn & 7) << 4)));
      }
      #pragma unroll
      for (int fm = 0; fm < 4; ++fm)
        #pragma unroll
        for (int fn = 0; fn < 4; ++fn)
          acc[fm][fn] = __builtin_amdgcn_mfma_f32_16x16x32_bf16(af[fm], bfr[fn], acc[fm][fn], 0, 0, 0);
    }
  }

  #pragma unroll
  for (int fm = 0; fm < 4; ++fm) {
    const int m = bm + wr*64 + fm*16 + lg*4;
    #pragma unroll
    for (int fn = 0; fn < 4; ++fn) {
      const int n = bn + wc*64 + fn*16 + lr;
      #pragma unroll
      for (int r = 0; r < 4; ++r) {
        if constexpr (B16OUT)
          ((ushort_t*)Cv)[(size_t)(m + r)*ldc + n] = f2bf(acc[fm][fn][r]);
        else
          ((float*)Cv)[(size_t)(m + r)*ldc + n] = acc[fm][fn][r];
      }
    }
  }
}

// RoPE on bf16 QKV; writes Qo (SM_SCALE*LOG2E folded -> softmax in exp2 domain)
// and Ko[b,hk][s][d].
__global__ __launch_bounds__(256) void rope_conv(
    const ushort_t* __restrict__ QKVb, ushort_t* __restrict__ Qo,
    ushort_t* __restrict__ Ko)
{
  const int total = NTOK * (NH + NKV) * (HD/2);
  int idx = blockIdx.x * 256 + threadIdx.x;
  if (idx >= total) return;
  const int i   = idx & 63;
  int tmp = idx >> 6;
  const int hs  = tmp % (NH + NKV);
  const int tkn = tmp / (NH + NKV);
  const int s   = tkn & (SEQ - 1);
  const int b   = tkn >> 11;
  const float invf = expf(-(float)i * 0.14391156831212787f);
  float sn, cs;
  sincosf((float)s * invf, &sn, &cs);
  const size_t base = (size_t)tkn * QKV_LD + (hs < NH ? hs * HD : KOFF + (hs - NH) * HD);
  const float x0 = bf2f(QKVb[base + i]);
  const float x1 = bf2f(QKVb[base + i + 64]);
  const float y0 = x0 * cs - x1 * sn;
  const float y1 = x1 * cs + x0 * sn;
  if (hs < NH) {
    ushort_t* q = Qo + (size_t)tkn * HIDDEN + hs * HD;
    q[i]      = f2bf(y0 * (SM_SCALE * LOG2E));
    q[i + 64] = f2bf(y1 * (SM_SCALE * LOG2E));
  } else {
    ushort_t* k = Ko + ((size_t)(b*NKV + (hs - NH))*SEQ + s) * HD;
    k[i]      = f2bf(y0);
    k[i + 64] = f2bf(y1);
  }
}

// V columns of QKVb -> Vtb[b,hk][d][s]
__global__ __launch_bounds__(256) void vt_conv(
    const ushort_t* __restrict__ QKVb, ushort_t* __restrict__ Vtb)
{
  __shared__ ushort_t tile[32][33];
  const int s0 = blockIdx.x*32;
  const int d0 = (blockIdx.y & 3)*32;
  const int bk = blockIdx.y >> 2;
  const int b = bk >> 2, hk = bk & 3;
  const int tx = threadIdx.x & 31, ty = threadIdx.x >> 5;
  #pragma unroll
  for (int i = 0; i < 4; ++i) {
    const int sl = ty*4 + i;
    tile[sl][tx] = QKVb[(size_t)(b*SEQ + s0 + sl)*QKV_LD + VOFF + hk*HD + d0 + tx];
  }
  __syncthreads();
  #pragma unroll
  for (int i = 0; i < 4; ++i) {
    const int dl = ty*4 + i;
    Vtb[((size_t)bk*HD + d0 + dl)*SEQ + s0 + tx] = tile[tx][dl];
  }
}

// ---------------- MFMA flash attention v8: v7 + key-split for long q-tiles ----
// Block = 4 waves = 4 q-heads of one hk, one 32-row q-tile (v7 inner math).
// qt < 32: single block, direct output (v7 path).
// qt >= 32: TWO blocks split the key range at h = (nsteps+1)/2; each writes
// unnormalized partials (O bf16, m/l f32) to ws; merge_attn combines.
// Work spread 1..32 -> 1..17 steps over 768 blocks (3 resident/CU) -> tail packs.
// Chunk0 has no masked tile; chunk1 contains the diagonal and every q-row
// attends >=1 real key there (h*64 <= qt*32 for qt>=2) -> m finite.
__global__ __launch_bounds__(256) void attn_mfma8(
    const ushort_t* __restrict__ Qb, const ushort_t* __restrict__ Kb,
    const ushort_t* __restrict__ Vtb, ushort_t* __restrict__ O,
    ushort_t* __restrict__ Po, float2* __restrict__ ML)
{
  __shared__ char smem[49152];   // K 16K | V 16K | P 4x4K

  const int bx = blockIdx.x;                // b*NKV + hk
  const int y  = blockIdx.y;
  int qt, chunk; bool dual;
  if (y < 64) { qt = 63 - (y >> 1); chunk = y & 1; dual = true; }   // qt 32..63
  else        { qt = 95 - y;        chunk = 0;     dual = false; }  // qt 31..0
  const int b = bx >> 2, hk = bx & 3;
  const int t = threadIdx.x, w = t >> 6, lane = t & 63;
  const int c = lane & 31, hi = lane >> 5;
  const int h = hk*4 + w;                   // this wave's q-head
  const int qw0 = qt*32;
  const int qg  = qw0 + c;
  const int nsteps = (qt + 2) >> 1;         // 64-key tiles for this q-tile
  const int half = (nsteps + 1) >> 1;
  const int k0 = (dual && chunk == 1) ? half : 0;
  const int k1 = (dual && chunk == 0) ? half : nsteps;

  const char* Kbb = (const char*)(Kb + (size_t)(b*NKV + hk)*SEQ*HD);
  const char* Vbb = (const char*)(Vtb + (size_t)(b*NKV + hk)*HD*SEQ);
  char* klds = smem;
  char* vlds = smem + 16384;
  char* plb  = smem + 32768 + w*4096;

  int ksrc[4], vsrc[4], ldst[4];
  #pragma unroll
  for (int u = 0; u < 4; ++u) {
    const int idx = u*256 + t;
    const int krow = idx >> 4, kof = (idx & 15) << 4;   // K: 64 rows x 256B
    ksrc[u] = krow*256 + (kof ^ ((krow & 15) << 4));
    const int vd = idx >> 3,  vof = (idx & 7) << 4;     // V: 128 dim-rows x 128B
    vsrc[u] = vd*(SEQ*2) + (vof ^ ((vd & 7) << 4));
    ldst[u] = idx*16;
  }

  bf16x8 qf[8];
  {
    const ushort_t* qrow = Qb + (size_t)(b*SEQ + qg)*HIDDEN + h*HD;
    #pragma unroll
    for (int kc = 0; kc < 8; ++kc)
      qf[kc] = *(const bf16x8*)(qrow + kc*16 + hi*8);
  }

  f32x16 ot[4];
  #pragma unroll
  for (int nc = 0; nc < 4; ++nc)
    #pragma unroll
    for (int r = 0; r < 16; ++r) ot[nc][r] = 0.f;
  float m = -1e30f, l = 0.f;

  // stage first tile of this chunk
  {
    const size_t kto = (size_t)k0 * 16384;
    const int    vto = k0 * 128;
    #pragma unroll
    for (int u = 0; u < 4; ++u) {
      gload16(Kbb + kto + ksrc[u], klds + ldst[u]);
      gload16(Vbb + vto + vsrc[u], vlds + ldst[u]);
    }
  }
  __syncthreads();   // vmcnt(0) drain + barrier

  for (int kt = k0; kt < k1; ++kt) {
    // ---- QK^T (swapped): D col = q-row, rows = keys
    f32x16 s[2];
    #pragma unroll
    for (int kn = 0; kn < 2; ++kn)
      #pragma unroll
      for (int r = 0; r < 16; ++r) s[kn][r] = 0.f;
    #pragma unroll
    for (int kn = 0; kn < 2; ++kn) {
      const int row = kn*32 + c;
      const int sw = (row & 15) << 4;
      #pragma unroll
      for (int kc = 0; kc < 8; ++kc) {
        const bf16x8 ka = *(const bf16x8*)(klds + row*256 + ((kc*32 + hi*16) ^ sw));
        s[kn] = __builtin_amdgcn_mfma_f32_32x32x16_bf16(ka, qf[kc], s[kn], 0, 0, 0);
      }
    }
    // ---- causal mask: only the global last tile (chunk0 of a dual never hits it)
    if (kt == nsteps - 1) {
      #pragma unroll
      for (int kn = 0; kn < 2; ++kn)
        #pragma unroll
        for (int r = 0; r < 16; ++r) {
          const int kg_ = kt*64 + kn*32 + (r & 3) + 8*(r >> 2) + 4*hi;
          if (kg_ > qg) s[kn][r] = -1e30f;
        }
    }
    // ---- online softmax (exp2 domain, lane-local per q-row; m identical across hi)
    float mx[16];
    #pragma unroll
    for (int r = 0; r < 16; ++r) mx[r] = fmaxf(s[0][r], s[1][r]);
    #pragma unroll
    for (int st = 8; st > 0; st >>= 1)
      #pragma unroll
      for (int r = 0; r < 8; ++r)
        if (r < st) mx[r] = fmaxf(mx[r], mx[r + st]);
    const float pm = fmaxf(mx[0], __shfl_xor(mx[0], 32));
    if (!__all(pm - m <= 8.f)) {     // T13 defer-max
      const float mnew = fmaxf(m, pm);
      const float corr = exp2f(m - mnew);
      m = mnew;
      l *= corr;
      #pragma unroll
      for (int nc = 0; nc < 4; ++nc) ot[nc] *= corr;
    }
    float ls = 0.f;
    #pragma unroll
    for (int kn = 0; kn < 2; ++kn)
      #pragma unroll
      for (int r = 0; r < 16; ++r) {
        const float p = exp2f(s[kn][r] - m);
        ls += p;
        s[kn][r] = p;
      }
    l += ls;
    // ---- P^T -> Pl[qrow][key] (wave-private region)
    {
      const int swp = (c & 7) << 4;
      #pragma unroll
      for (int kn = 0; kn < 2; ++kn)
        #pragma unroll
        for (int r = 0; r < 16; r += 2) {
          const int key = kn*32 + (r & 3) + 8*(r >> 2) + 4*hi;
          *(unsigned*)(plb + c*128 + ((key*2) ^ swp)) = pack2(s[kn][r], s[kn][r+1]);
        }
    }
    asm volatile("s_waitcnt lgkmcnt(0)" ::: "memory");   // own-wave Pl write->read
    // ---- PV: O^T += V^T . P^T
    #pragma unroll
    for (int kc = 0; kc < 4; ++kc) {
      const bf16x8 pb = *(const bf16x8*)(plb + c*128 + ((kc*32 + hi*16) ^ ((c & 7) << 4)));
      #pragma unroll
      for (int nc = 0; nc < 4; ++nc) {
        const int dim = nc*32 + c;
        const bf16x8 va = *(const bf16x8*)(vlds + dim*128 + ((kc*32 + hi*16) ^ ((dim & 7) << 4)));
        ot[nc] = __builtin_amdgcn_mfma_f32_32x32x16_bf16(va, pb, ot[nc], 0, 0, 0);
      }
    }
    // ---- stage next tile (single buffer)
    if (kt < k1 - 1) {
      __syncthreads();
      const size_t kto = (size_t)(kt + 1) * 16384;
      const int    vto = (kt + 1) * 128;
      #pragma unroll
      for (int u = 0; u < 4; ++u) {
        gload16(Kbb + kto + ksrc[u], klds + ldst[u]);
        gload16(Vbb + vto + vsrc[u], vlds + ldst[u]);
      }
      __syncthreads();
    }
  }

  const float lt = l + __shfl_xor(l, 32);   // full sum over this chunk's keys
  if (!dual) {
    // direct output (v7 epilogue)
    const float inv = 1.f / lt;
    ushort_t* orow = O + (size_t)(b*SEQ + qg) * HIDDEN + h*HD;
    #pragma unroll
    for (int nc = 0; nc < 4; ++nc)
      #pragma unroll
      for (int r = 0; r < 16; r += 2) {
        const int dim = nc*32 + (r & 3) + 8*(r >> 2) + 4*hi;
        *(unsigned*)(orow + dim) = pack2(ot[nc][r]*inv, ot[nc][r+1]*inv);
      }
  } else {
    // partial record: rec in [0, 32768) + chunk*32768
    const int rec = (((qt - 32)*8 + bx)*4 + w)*32 + c + chunk*32768;
    ushort_t* orow = Po + (size_t)rec * 128;
    #pragma unroll
    for (int nc = 0; nc < 4; ++nc)
      #pragma unroll
      for (int r = 0; r < 16; r += 2) {
        const int dim = nc*32 + (r & 3) + 8*(r >> 2) + 4*hi;
        *(unsigned*)(orow + dim) = pack2(ot[nc][r], ot[nc][r+1]);   // unnormalized
      }
    if (hi == 0) ML[rec] = make_float2(m, lt);
  }
}

// Combine the two key-chunks of each qt>=32 record: O = (o0*e0 + o1*e1)/(l0*e0 + l1*e1)
__global__ __launch_bounds__(256) void merge_attn(
    const ushort_t* __restrict__ Po, const float2* __restrict__ ML,
    ushort_t* __restrict__ Oat)
{
  const int rec  = blockIdx.x*4 + (threadIdx.x >> 6);
  const int lane = threadIdx.x & 63;
  const float2 ml0 = ML[rec], ml1 = ML[rec + 32768];
  const float ms = fmaxf(ml0.x, ml1.x);
  const float w0 = exp2f(ml0.x - ms), w1 = exp2f(ml1.x - ms);
  const float inv = 1.f / (ml0.y*w0 + ml1.y*w1);
  const int c  = rec & 31, wv = (rec >> 5) & 3, bx = (rec >> 7) & 7, qt = 32 + (rec >> 10);
  const int b = bx >> 2, hk = bx & 3, hh = hk*4 + wv;
  const ushort_t* p0 = Po + (size_t)rec * 128;
  const ushort_t* p1 = p0 + (size_t)32768 * 128;
  ushort_t* dst = Oat + (size_t)(b*SEQ + qt*32 + c)*HIDDEN + hh*HD;
  const int d = lane*2;
  const float a0 = bf2f(p0[d]), a1 = bf2f(p0[d+1]);
  const float b0 = bf2f(p1[d]), b1 = bf2f(p1[d+1]);
  *(unsigned*)(dst + d) = pack2((a0*w0 + b0*w1)*inv, (a1*w0 + b1*w1)*inv);
}

extern "C" void kernel_launch(void* const* d_in, const int* in_sizes, int n_in,
                              void* d_out, int out_size, void* d_ws, size_t ws_size,
                              hipStream_t stream)
{
  (void)in_sizes; (void)n_in; (void)out_size; (void)ws_size;
  const float* H  = (const float*)d_in[0];
  const float* Wq = (const float*)d_in[1];
  const float* Wk = (const float*)d_in[2];
  const float* Wv = (const float*)d_in[3];
  const float* Wo = (const float*)d_in[4];
  float* out = (float*)d_out;

  char* ws = (char*)d_ws;
  ushort_t* QKVb = (ushort_t*)ws;                      // [4096][3072] bf16  25.2 MB
  ushort_t* Hb   = (ushort_t*)(ws + 25165824);         // [4096][2048] bf16  (dead after gemm -> Qb)
  ushort_t* Qb   = Hb;
  ushort_t* Wt   = (ushort_t*)(ws + 41943040);         // [3072][2048] bf16  (reused for Wo)
  ushort_t* Kb   = (ushort_t*)(ws + 54525952);         // [2*4][2048][128]
  ushort_t* Vtb  = (ushort_t*)(ws + 58720256);         // [2*4][128][2048]
  ushort_t* Oat  = (ushort_t*)(ws + 62914560);         // [4096][2048] bf16
  // attn partials overlay the DEAD QKVb region (QKVb unread after rope/vt_conv):
  ushort_t* Po   = (ushort_t*)ws;                      // 65536 x 128 bf16 = 16.8 MB
  float2*   ML   = (float2*)(ws + 16777216);           // 65536 x 8 B      = 0.5 MB

  conv_f2b<<<4096, 256, 0, stream>>>(H, Hb, NTOK*HIDDEN/8);
  transpose_f2b<<<dim3(64, 64), 256, 0, stream>>>(Wq, Wt,                     2048, 2048);
  transpose_f2b<<<dim3(16, 64), 256, 0, stream>>>(Wk, Wt + (size_t)2048*2048, 2048, 512);
  transpose_f2b<<<dim3(16, 64), 256, 0, stream>>>(Wv, Wt + (size_t)2560*2048, 2048, 512);

  bt_gemm<true><<<dim3(QKV_LD/128, NTOK/128), 256, 0, stream>>>(Hb, Wt, QKVb, QKV_LD);

  const int rope_total = NTOK * (NH + NKV) * (HD/2);
  rope_conv<<<(rope_total + 255)/256, 256, 0, stream>>>(QKVb, Qb, Kb);
  vt_conv<<<dim3(SEQ/32, 32), 256, 0, stream>>>(QKVb, Vtb);

  attn_mfma8<<<dim3(8, 96), 256, 0, stream>>>(Qb, Kb, Vtb, Oat, Po, ML);
  merge_attn<<<8192, 256, 0, stream>>>(Po, ML, Oat);

  transpose_f2b<<<dim3(64, 64), 256, 0, stream>>>(Wo, Wt, 2048, 2048);
  bt_gemm<false><<<dim3(HIDDEN/128, NTOK/128), 256, 0, stream>>>(Oat, Wt, out, HIDDEN);
}

// Round 12
// 261.193 us; speedup vs baseline: 1.0322x; 1.0322x over previous
//
#include <hip/hip_runtime.h>
#include <hip/hip_bf16.h>
#include <cstdint>
#include <cstddef>

#define HIDDEN   2048
#define NH       16
#define NKV      4
#define HD       128
#define SEQ      2048
#define BATCH    2
#define NTOK     (BATCH*SEQ)      // 4096
#define QKV_LD   3072             // Q(2048) | K(512) | V(512)
#define KOFF     2048
#define VOFF     2560
#define SM_SCALE 0.08838834764831845f   // 1/sqrt(128)
#define LOG2E    1.4426950408889634f

typedef __attribute__((ext_vector_type(8)))  short bf16x8;
typedef __attribute__((ext_vector_type(4)))  float f32x4v;
typedef __attribute__((ext_vector_type(16))) float f32x16;
typedef unsigned short ushort_t;

__device__ __forceinline__ unsigned short f2bf(float f) {
  return __builtin_bit_cast(unsigned short, __float2bfloat16(f));
}
__device__ __forceinline__ float bf2f(ushort_t u) {
  return __builtin_bit_cast(float, (unsigned)u << 16);
}
__device__ __forceinline__ unsigned pack2(float a, float b) {
  return (unsigned)f2bf(a) | ((unsigned)f2bf(b) << 16);
}

// async global->LDS, 16B/lane; LDS dest lane-linear, swizzle realized on the GLOBAL src.
__device__ __forceinline__ void gload16(const void* g, void* l) {
  __builtin_amdgcn_global_load_lds(
      (const __attribute__((address_space(1))) unsigned int*)g,
      (__attribute__((address_space(3))) unsigned int*)l, 16, 0, 0);
}

// ---------------- conversion kernels ----------------
__global__ __launch_bounds__(256) void conv_f2b(
    const float* __restrict__ in, ushort_t* __restrict__ out, int n8)
{
  const int i = blockIdx.x*256 + threadIdx.x;
  if (i >= n8) return;
  const float4 a = ((const float4*)in)[2*i];
  const float4 b = ((const float4*)in)[2*i + 1];
  uint4 r;
  r.x = pack2(a.x, a.y); r.y = pack2(a.z, a.w);
  r.z = pack2(b.x, b.y); r.w = pack2(b.z, b.w);
  ((uint4*)out)[i] = r;
}

// W[K][N] fp32 -> Wt[N][K] bf16
__global__ __launch_bounds__(256) void transpose_f2b(
    const float* __restrict__ W, ushort_t* __restrict__ Wt, int K, int N)
{
  __shared__ float tile[32][33];
  const int n0 = blockIdx.x*32, k0 = blockIdx.y*32;
  const int tx = threadIdx.x & 31, ty = threadIdx.x >> 5;
  #pragma unroll
  for (int i = 0; i < 4; ++i)
    tile[ty*4 + i][tx] = W[(size_t)(k0 + ty*4 + i)*N + n0 + tx];
  __syncthreads();
  #pragma unroll
  for (int i = 0; i < 4; ++i) {
    const int nl = ty*4 + i;
    Wt[(size_t)(n0 + nl)*K + k0 + tx] = f2bf(tile[tx][nl]);
  }
}

// ---------------- bf16 MFMA GEMM (m97 structure), templated output dtype --------
template<bool B16OUT>
__global__ __launch_bounds__(256) void bt_gemm(
    const ushort_t* __restrict__ A, const ushort_t* __restrict__ Bt,
    void* __restrict__ Cv, int ldc)
{
  __shared__ ushort_t As[128*64];
  __shared__ ushort_t Bs[128*64];
  const int t = threadIdx.x, lane = t & 63, w = t >> 6;
  const int bm = blockIdx.y*128, bn = blockIdx.x*128;
  const int wr = w >> 1, wc = w & 1;
  const int lr = lane & 15, lg = lane >> 4;

  f32x4v acc[4][4];
  #pragma unroll
  for (int fm = 0; fm < 4; ++fm)
    #pragma unroll
    for (int fn = 0; fn < 4; ++fn)
      #pragma unroll
      for (int r = 0; r < 4; ++r) acc[fm][fn][r] = 0.f;

  const char* Ab = (const char*)A;
  const char* Bb = (const char*)Bt;
  char* asb = (char*)As;
  char* bsb = (char*)Bs;

  for (int kt = 0; kt < HIDDEN*2; kt += 128) {
    __syncthreads();
    #pragma unroll
    for (int u = 0; u < 4; ++u) {
      const int idx = u*256 + t;
      const int row = idx >> 3;
      const int kb  = (idx & 7) * 16;
      const int skb = kb ^ ((row & 7) << 4);
      gload16(Ab + (size_t)(bm + row)*4096 + kt + skb, asb + idx*16);
      gload16(Bb + (size_t)(bn + row)*4096 + kt + skb, bsb + idx*16);
    }
    __syncthreads();
    #pragma unroll
    for (int kc = 0; kc < 2; ++kc) {
      bf16x8 af[4], bfr[4];
      #pragma unroll
      for (int f = 0; f < 4; ++f) {
        const int rm = wr*64 + f*16 + lr;
        af[f]  = *(const bf16x8*)(asb + rm*128 + ((kc*64 + lg*16) ^ ((rm & 7) << 4)));
        const int rn = wc*64 + f*16 + lr;
        bfr[f] = *(const bf16x8*)(bsb + rn*128 + ((kc*64 + lg*16) ^ ((rn & 7) << 4)));
      }
      #pragma unroll
      for (int fm = 0; fm < 4; ++fm)
        #pragma unroll
        for (int fn = 0; fn < 4; ++fn)
          acc[fm][fn] = __builtin_amdgcn_mfma_f32_16x16x32_bf16(af[fm], bfr[fn], acc[fm][fn], 0, 0, 0);
    }
  }

  #pragma unroll
  for (int fm = 0; fm < 4; ++fm) {
    const int m = bm + wr*64 + fm*16 + lg*4;
    #pragma unroll
    for (int fn = 0; fn < 4; ++fn) {
      const int n = bn + wc*64 + fn*16 + lr;
      #pragma unroll
      for (int r = 0; r < 4; ++r) {
        if constexpr (B16OUT)
          ((ushort_t*)Cv)[(size_t)(m + r)*ldc + n] = f2bf(acc[fm][fn][r]);
        else
          ((float*)Cv)[(size_t)(m + r)*ldc + n] = acc[fm][fn][r];
      }
    }
  }
}

// RoPE on bf16 QKV; writes Qo (SM_SCALE*LOG2E folded -> softmax in exp2 domain)
// and Ko[b,hk][s][d].
__global__ __launch_bounds__(256) void rope_conv(
    const ushort_t* __restrict__ QKVb, ushort_t* __restrict__ Qo,
    ushort_t* __restrict__ Ko)
{
  const int total = NTOK * (NH + NKV) * (HD/2);
  int idx = blockIdx.x * 256 + threadIdx.x;
  if (idx >= total) return;
  const int i   = idx & 63;
  int tmp = idx >> 6;
  const int hs  = tmp % (NH + NKV);
  const int tkn = tmp / (NH + NKV);
  const int s   = tkn & (SEQ - 1);
  const int b   = tkn >> 11;
  const float invf = expf(-(float)i * 0.14391156831212787f);
  float sn, cs;
  sincosf((float)s * invf, &sn, &cs);
  const size_t base = (size_t)tkn * QKV_LD + (hs < NH ? hs * HD : KOFF + (hs - NH) * HD);
  const float x0 = bf2f(QKVb[base + i]);
  const float x1 = bf2f(QKVb[base + i + 64]);
  const float y0 = x0 * cs - x1 * sn;
  const float y1 = x1 * cs + x0 * sn;
  if (hs < NH) {
    ushort_t* q = Qo + (size_t)tkn * HIDDEN + hs * HD;
    q[i]      = f2bf(y0 * (SM_SCALE * LOG2E));
    q[i + 64] = f2bf(y1 * (SM_SCALE * LOG2E));
  } else {
    ushort_t* k = Ko + ((size_t)(b*NKV + (hs - NH))*SEQ + s) * HD;
    k[i]      = f2bf(y0);
    k[i + 64] = f2bf(y1);
  }
}

// V columns of QKVb -> Vtb[b,hk][d][s]
__global__ __launch_bounds__(256) void vt_conv(
    const ushort_t* __restrict__ QKVb, ushort_t* __restrict__ Vtb)
{
  __shared__ ushort_t tile[32][33];
  const int s0 = blockIdx.x*32;
  const int d0 = (blockIdx.y & 3)*32;
  const int bk = blockIdx.y >> 2;
  const int b = bk >> 2, hk = bk & 3;
  const int tx = threadIdx.x & 31, ty = threadIdx.x >> 5;
  #pragma unroll
  for (int i = 0; i < 4; ++i) {
    const int sl = ty*4 + i;
    tile[sl][tx] = QKVb[(size_t)(b*SEQ + s0 + sl)*QKV_LD + VOFF + hk*HD + d0 + tx];
  }
  __syncthreads();
  #pragma unroll
  for (int i = 0; i < 4; ++i) {
    const int dl = ty*4 + i;
    Vtb[((size_t)bk*HD + d0 + dl)*SEQ + s0 + tx] = tile[tx][dl];
  }
}

// ---------------- MFMA flash attention v9: v7 + double-buffered K/V ----------
// Block = 4 waves (256 thr) = the 4 q-heads of one hk, ONE 32-row q-tile;
// K/V tile (64 keys) staged once per hk (GQA reuse). DOUBLE-buffered: tile t+1's
// global_load_lds issues BEFORE computing tile t, so the end-of-step barrier's
// vmcnt drain happens after ~a full compute phase has covered the load latency
// (v7's stage->drain->compute serialization was the per-step cost).
// LDS 80 KB -> 2 blocks/CU; grid 512 -> ALL blocks resident.
// qt remap (y<32 ? 63-y : y-32): co-resident block pair (round-robin CU
// assignment heuristic) sums to a constant 33 steps -> balanced without tail.
__global__ __launch_bounds__(256) void attn_mfma9(
    const ushort_t* __restrict__ Qb, const ushort_t* __restrict__ Kb,
    const ushort_t* __restrict__ Vtb, ushort_t* __restrict__ O)
{
  // [0,16384)      Kl buf0   [16384,32768) Kl buf1
  // [32768,49152)  Vl buf0   [49152,65536) Vl buf1
  // [65536,81920)  Pl: 4 waves x [32 q-rows][128B] (swz ^((c&7)<<4))
  __shared__ char smem[81920];

  const int bx = blockIdx.x;                // b*NKV + hk
  const int y  = blockIdx.y;
  const int qt = (y < 32) ? (63 - y) : (y - 32);
  const int b = bx >> 2, hk = bx & 3;
  const int t = threadIdx.x, w = t >> 6, lane = t & 63;
  const int c = lane & 31, hi = lane >> 5;
  const int h = hk*4 + w;                   // this wave's q-head
  const int qw0 = qt*32;
  const int qg  = qw0 + c;
  const int nsteps = (qt + 2) >> 1;         // ceil((qt+1)/2) 64-key tiles

  const char* Kbb = (const char*)(Kb + (size_t)(b*NKV + hk)*SEQ*HD);
  const char* Vbb = (const char*)(Vtb + (size_t)(b*NKV + hk)*HD*SEQ);
  char* plb  = smem + 65536 + w*4096;

  // staging offsets: 256 threads, 4 x 16B slots each per K and V tile
  int ksrc[4], vsrc[4], ldst[4];
  #pragma unroll
  for (int u = 0; u < 4; ++u) {
    const int idx = u*256 + t;
    const int krow = idx >> 4, kof = (idx & 15) << 4;   // K: 64 rows x 256B
    ksrc[u] = krow*256 + (kof ^ ((krow & 15) << 4));
    const int vd = idx >> 3,  vof = (idx & 7) << 4;     // V: 128 dim-rows x 128B
    vsrc[u] = vd*(SEQ*2) + (vof ^ ((vd & 7) << 4));
    ldst[u] = idx*16;
  }

  bf16x8 qf[8];
  {
    const ushort_t* qrow = Qb + (size_t)(b*SEQ + qg)*HIDDEN + h*HD;
    #pragma unroll
    for (int kc = 0; kc < 8; ++kc)
      qf[kc] = *(const bf16x8*)(qrow + kc*16 + hi*8);
  }

  f32x16 ot[4];
  #pragma unroll
  for (int nc = 0; nc < 4; ++nc)
    #pragma unroll
    for (int r = 0; r < 16; ++r) ot[nc][r] = 0.f;
  float m = -1e30f, l = 0.f;

  // prologue: stage tile 0 into buf 0
  #pragma unroll
  for (int u = 0; u < 4; ++u) {
    gload16(Kbb + ksrc[u], smem + ldst[u]);
    gload16(Vbb + vsrc[u], smem + 32768 + ldst[u]);
  }
  __syncthreads();   // vmcnt(0) drain + barrier

  int cur = 0;
  for (int kt = 0; kt < nsteps; ++kt) {
    // ---- issue next tile's loads into the other buffer BEFORE computing
    if (kt + 1 < nsteps) {
      const int nb = cur ^ 1;
      const size_t kto = (size_t)(kt + 1) * 16384;   // 64 keys * 256B
      const int    vto = (kt + 1) * 128;             // 64 keys * 2B within V rows
      #pragma unroll
      for (int u = 0; u < 4; ++u) {
        gload16(Kbb + kto + ksrc[u], smem + nb*16384 + ldst[u]);
        gload16(Vbb + vto + vsrc[u], smem + 32768 + nb*16384 + ldst[u]);
      }
    }
    const char* klds = smem + cur*16384;
    const char* vlds = smem + 32768 + cur*16384;
    // ---- QK^T (swapped): D col = q-row, rows = keys
    f32x16 s[2];
    #pragma unroll
    for (int kn = 0; kn < 2; ++kn)
      #pragma unroll
      for (int r = 0; r < 16; ++r) s[kn][r] = 0.f;
    #pragma unroll
    for (int kn = 0; kn < 2; ++kn) {
      const int row = kn*32 + c;
      const int sw = (row & 15) << 4;
      #pragma unroll
      for (int kc = 0; kc < 8; ++kc) {
        const bf16x8 ka = *(const bf16x8*)(klds + row*256 + ((kc*32 + hi*16) ^ sw));
        s[kn] = __builtin_amdgcn_mfma_f32_32x32x16_bf16(ka, qf[kc], s[kn], 0, 0, 0);
      }
    }
    // ---- causal mask: only the last tile can cross the diagonal.
    if (kt == nsteps - 1) {
      #pragma unroll
      for (int kn = 0; kn < 2; ++kn)
        #pragma unroll
        for (int r = 0; r < 16; ++r) {
          const int kg_ = kt*64 + kn*32 + (r & 3) + 8*(r >> 2) + 4*hi;
          if (kg_ > qg) s[kn][r] = -1e30f;
        }
    }
    // ---- online softmax (exp2 domain, lane-local per q-row)
    float mx[16];
    #pragma unroll
    for (int r = 0; r < 16; ++r) mx[r] = fmaxf(s[0][r], s[1][r]);
    #pragma unroll
    for (int st = 8; st > 0; st >>= 1)
      #pragma unroll
      for (int r = 0; r < 8; ++r)
        if (r < st) mx[r] = fmaxf(mx[r], mx[r + st]);
    const float pm = fmaxf(mx[0], __shfl_xor(mx[0], 32));
    // T13 defer-max: skip O/l rescale while max growth <= 8 (P <= 2^8, fp32-safe)
    if (!__all(pm - m <= 8.f)) {
      const float mnew = fmaxf(m, pm);
      const float corr = exp2f(m - mnew);
      m = mnew;
      l *= corr;
      #pragma unroll
      for (int nc = 0; nc < 4; ++nc) ot[nc] *= corr;
    }
    float ls = 0.f;
    #pragma unroll
    for (int kn = 0; kn < 2; ++kn)
      #pragma unroll
      for (int r = 0; r < 16; ++r) {
        const float p = exp2f(s[kn][r] - m);
        ls += p;
        s[kn][r] = p;
      }
    l += ls;
    // ---- P^T -> Pl[qrow][key] (wave-private region)
    {
      const int swp = (c & 7) << 4;
      #pragma unroll
      for (int kn = 0; kn < 2; ++kn)
        #pragma unroll
        for (int r = 0; r < 16; r += 2) {
          const int key = kn*32 + (r & 3) + 8*(r >> 2) + 4*hi;
          *(unsigned*)(plb + c*128 + ((key*2) ^ swp)) = pack2(s[kn][r], s[kn][r+1]);
        }
    }
    asm volatile("s_waitcnt lgkmcnt(0)" ::: "memory");   // own-wave Pl write->read
    // ---- PV: O^T += V^T . P^T
    #pragma unroll
    for (int kc = 0; kc < 4; ++kc) {
      const bf16x8 pb = *(const bf16x8*)(plb + c*128 + ((kc*32 + hi*16) ^ ((c & 7) << 4)));
      #pragma unroll
      for (int nc = 0; nc < 4; ++nc) {
        const int dim = nc*32 + c;
        const bf16x8 va = *(const bf16x8*)(vlds + dim*128 + ((kc*32 + hi*16) ^ ((dim & 7) << 4)));
        ot[nc] = __builtin_amdgcn_mfma_f32_32x32x16_bf16(va, pb, ot[nc], 0, 0, 0);
      }
    }
    // ---- end of step: next-tile loads drained (after a full compute phase of
    // overlap) + all waves done with buf cur before it is overwritten next step
    __syncthreads();
    cur ^= 1;
  }

  // ---- epilogue (per-wave; outputs disjoint)
  const float lt = l + __shfl_xor(l, 32);
  const float inv = 1.f / lt;
  ushort_t* orow = O + (size_t)(b*SEQ + qg) * HIDDEN + h*HD;
  #pragma unroll
  for (int nc = 0; nc < 4; ++nc)
    #pragma unroll
    for (int r = 0; r < 16; r += 2) {
      const int dim = nc*32 + (r & 3) + 8*(r >> 2) + 4*hi;
      *(unsigned*)(orow + dim) = pack2(ot[nc][r]*inv, ot[nc][r+1]*inv);
    }
}

extern "C" void kernel_launch(void* const* d_in, const int* in_sizes, int n_in,
                              void* d_out, int out_size, void* d_ws, size_t ws_size,
                              hipStream_t stream)
{
  (void)in_sizes; (void)n_in; (void)out_size; (void)ws_size;
  const float* H  = (const float*)d_in[0];
  const float* Wq = (const float*)d_in[1];
  const float* Wk = (const float*)d_in[2];
  const float* Wv = (const float*)d_in[3];
  const float* Wo = (const float*)d_in[4];
  float* out = (float*)d_out;

  char* ws = (char*)d_ws;
  ushort_t* QKVb = (ushort_t*)ws;                      // [4096][3072] bf16  25.2 MB
  ushort_t* Hb   = (ushort_t*)(ws + 25165824);         // [4096][2048] bf16  (dead after gemm -> Qb)
  ushort_t* Qb   = Hb;
  ushort_t* Wt   = (ushort_t*)(ws + 41943040);         // [3072][2048] bf16  (reused for Wo)
  ushort_t* Kb   = (ushort_t*)(ws + 54525952);         // [2*4][2048][128]
  ushort_t* Vtb  = (ushort_t*)(ws + 58720256);         // [2*4][128][2048]
  ushort_t* Oat  = (ushort_t*)(ws + 62914560);         // [4096][2048] bf16

  conv_f2b<<<4096, 256, 0, stream>>>(H, Hb, NTOK*HIDDEN/8);
  transpose_f2b<<<dim3(64, 64), 256, 0, stream>>>(Wq, Wt,                     2048, 2048);
  transpose_f2b<<<dim3(16, 64), 256, 0, stream>>>(Wk, Wt + (size_t)2048*2048, 2048, 512);
  transpose_f2b<<<dim3(16, 64), 256, 0, stream>>>(Wv, Wt + (size_t)2560*2048, 2048, 512);

  bt_gemm<true><<<dim3(QKV_LD/128, NTOK/128), 256, 0, stream>>>(Hb, Wt, QKVb, QKV_LD);

  const int rope_total = NTOK * (NH + NKV) * (HD/2);
  rope_conv<<<(rope_total + 255)/256, 256, 0, stream>>>(QKVb, Qb, Kb);
  vt_conv<<<dim3(SEQ/32, 32), 256, 0, stream>>>(QKVb, Vtb);

  attn_mfma9<<<dim3(8, 64), 256, 0, stream>>>(Qb, Kb, Vtb, Oat);

  transpose_f2b<<<dim3(64, 64), 256, 0, stream>>>(Wo, Wt, 2048, 2048);
  bt_gemm<false><<<dim3(HIDDEN/128, NTOK/128), 256, 0, stream>>>(Oat, Wt, out, HIDDEN);
}

// Round 13
// 256.599 us; speedup vs baseline: 1.0507x; 1.0179x over previous
//
#include <hip/hip_runtime.h>
#include <hip/hip_bf16.h>
#include <cstdint>
#include <cstddef>

#define HIDDEN   2048
#define NH       16
#define NKV      4
#define HD       128
#define SEQ      2048
#define BATCH    2
#define NTOK     (BATCH*SEQ)      // 4096
#define QKV_LD   3072             // Q(2048) | K(512) | V(512)
#define KOFF     2048
#define VOFF     2560
#define SM_SCALE 0.08838834764831845f   // 1/sqrt(128)
#define LOG2E    1.4426950408889634f

typedef __attribute__((ext_vector_type(8)))  short bf16x8;
typedef __attribute__((ext_vector_type(4)))  float f32x4v;
typedef __attribute__((ext_vector_type(16))) float f32x16;
typedef unsigned short ushort_t;

__device__ __forceinline__ unsigned short f2bf(float f) {
  return __builtin_bit_cast(unsigned short, __float2bfloat16(f));
}
__device__ __forceinline__ float bf2f(ushort_t u) {
  return __builtin_bit_cast(float, (unsigned)u << 16);
}
__device__ __forceinline__ unsigned pack2(float a, float b) {
  return (unsigned)f2bf(a) | ((unsigned)f2bf(b) << 16);
}

// async global->LDS, 16B/lane; LDS dest lane-linear, swizzle realized on the GLOBAL src.
__device__ __forceinline__ void gload16(const void* g, void* l) {
  __builtin_amdgcn_global_load_lds(
      (const __attribute__((address_space(1))) unsigned int*)g,
      (__attribute__((address_space(3))) unsigned int*)l, 16, 0, 0);
}

// ---------------- conversion kernels ----------------
__global__ __launch_bounds__(256) void conv_f2b(
    const float* __restrict__ in, ushort_t* __restrict__ out, int n8)
{
  const int i = blockIdx.x*256 + threadIdx.x;
  if (i >= n8) return;
  const float4 a = ((const float4*)in)[2*i];
  const float4 b = ((const float4*)in)[2*i + 1];
  uint4 r;
  r.x = pack2(a.x, a.y); r.y = pack2(a.z, a.w);
  r.z = pack2(b.x, b.y); r.w = pack2(b.z, b.w);
  ((uint4*)out)[i] = r;
}

// W[K][N] fp32 -> Wt[N][K] bf16
__global__ __launch_bounds__(256) void transpose_f2b(
    const float* __restrict__ W, ushort_t* __restrict__ Wt, int K, int N)
{
  __shared__ float tile[32][33];
  const int n0 = blockIdx.x*32, k0 = blockIdx.y*32;
  const int tx = threadIdx.x & 31, ty = threadIdx.x >> 5;
  #pragma unroll
  for (int i = 0; i < 4; ++i)
    tile[ty*4 + i][tx] = W[(size_t)(k0 + ty*4 + i)*N + n0 + tx];
  __syncthreads();
  #pragma unroll
  for (int i = 0; i < 4; ++i) {
    const int nl = ty*4 + i;
    Wt[(size_t)(n0 + nl)*K + k0 + tx] = f2bf(tile[tx][nl]);
  }
}

// ---------------- bf16 MFMA GEMM (m97 structure), templated output dtype --------
template<bool B16OUT>
__global__ __launch_bounds__(256) void bt_gemm(
    const ushort_t* __restrict__ A, const ushort_t* __restrict__ Bt,
    void* __restrict__ Cv, int ldc)
{
  __shared__ ushort_t As[128*64];
  __shared__ ushort_t Bs[128*64];
  const int t = threadIdx.x, lane = t & 63, w = t >> 6;
  const int bm = blockIdx.y*128, bn = blockIdx.x*128;
  const int wr = w >> 1, wc = w & 1;
  const int lr = lane & 15, lg = lane >> 4;

  f32x4v acc[4][4];
  #pragma unroll
  for (int fm = 0; fm < 4; ++fm)
    #pragma unroll
    for (int fn = 0; fn < 4; ++fn)
      #pragma unroll
      for (int r = 0; r < 4; ++r) acc[fm][fn][r] = 0.f;

  const char* Ab = (const char*)A;
  const char* Bb = (const char*)Bt;
  char* asb = (char*)As;
  char* bsb = (char*)Bs;

  for (int kt = 0; kt < HIDDEN*2; kt += 128) {
    __syncthreads();
    #pragma unroll
    for (int u = 0; u < 4; ++u) {
      const int idx = u*256 + t;
      const int row = idx >> 3;
      const int kb  = (idx & 7) * 16;
      const int skb = kb ^ ((row & 7) << 4);
      gload16(Ab + (size_t)(bm + row)*4096 + kt + skb, asb + idx*16);
      gload16(Bb + (size_t)(bn + row)*4096 + kt + skb, bsb + idx*16);
    }
    __syncthreads();
    #pragma unroll
    for (int kc = 0; kc < 2; ++kc) {
      bf16x8 af[4], bfr[4];
      #pragma unroll
      for (int f = 0; f < 4; ++f) {
        const int rm = wr*64 + f*16 + lr;
        af[f]  = *(const bf16x8*)(asb + rm*128 + ((kc*64 + lg*16) ^ ((rm & 7) << 4)));
        const int rn = wc*64 + f*16 + lr;
        bfr[f] = *(const bf16x8*)(bsb + rn*128 + ((kc*64 + lg*16) ^ ((rn & 7) << 4)));
      }
      #pragma unroll
      for (int fm = 0; fm < 4; ++fm)
        #pragma unroll
        for (int fn = 0; fn < 4; ++fn)
          acc[fm][fn] = __builtin_amdgcn_mfma_f32_16x16x32_bf16(af[fm], bfr[fn], acc[fm][fn], 0, 0, 0);
    }
  }

  #pragma unroll
  for (int fm = 0; fm < 4; ++fm) {
    const int m = bm + wr*64 + fm*16 + lg*4;
    #pragma unroll
    for (int fn = 0; fn < 4; ++fn) {
      const int n = bn + wc*64 + fn*16 + lr;
      #pragma unroll
      for (int r = 0; r < 4; ++r) {
        if constexpr (B16OUT)
          ((ushort_t*)Cv)[(size_t)(m + r)*ldc + n] = f2bf(acc[fm][fn][r]);
        else
          ((float*)Cv)[(size_t)(m + r)*ldc + n] = acc[fm][fn][r];
      }
    }
  }
}

// RoPE on bf16 QKV; writes Qo (SM_SCALE*LOG2E folded -> softmax in exp2 domain)
// and Ko[b,hk][s][d].
__global__ __launch_bounds__(256) void rope_conv(
    const ushort_t* __restrict__ QKVb, ushort_t* __restrict__ Qo,
    ushort_t* __restrict__ Ko)
{
  const int total = NTOK * (NH + NKV) * (HD/2);
  int idx = blockIdx.x * 256 + threadIdx.x;
  if (idx >= total) return;
  const int i   = idx & 63;
  int tmp = idx >> 6;
  const int hs  = tmp % (NH + NKV);
  const int tkn = tmp / (NH + NKV);
  const int s   = tkn & (SEQ - 1);
  const int b   = tkn >> 11;
  const float invf = expf(-(float)i * 0.14391156831212787f);
  float sn, cs;
  sincosf((float)s * invf, &sn, &cs);
  const size_t base = (size_t)tkn * QKV_LD + (hs < NH ? hs * HD : KOFF + (hs - NH) * HD);
  const float x0 = bf2f(QKVb[base + i]);
  const float x1 = bf2f(QKVb[base + i + 64]);
  const float y0 = x0 * cs - x1 * sn;
  const float y1 = x1 * cs + x0 * sn;
  if (hs < NH) {
    ushort_t* q = Qo + (size_t)tkn * HIDDEN + hs * HD;
    q[i]      = f2bf(y0 * (SM_SCALE * LOG2E));
    q[i + 64] = f2bf(y1 * (SM_SCALE * LOG2E));
  } else {
    ushort_t* k = Ko + ((size_t)(b*NKV + (hs - NH))*SEQ + s) * HD;
    k[i]      = f2bf(y0);
    k[i + 64] = f2bf(y1);
  }
}

// V columns of QKVb -> Vtb[b,hk][d][s]
__global__ __launch_bounds__(256) void vt_conv(
    const ushort_t* __restrict__ QKVb, ushort_t* __restrict__ Vtb)
{
  __shared__ ushort_t tile[32][33];
  const int s0 = blockIdx.x*32;
  const int d0 = (blockIdx.y & 3)*32;
  const int bk = blockIdx.y >> 2;
  const int b = bk >> 2, hk = bk & 3;
  const int tx = threadIdx.x & 31, ty = threadIdx.x >> 5;
  #pragma unroll
  for (int i = 0; i < 4; ++i) {
    const int sl = ty*4 + i;
    tile[sl][tx] = QKVb[(size_t)(b*SEQ + s0 + sl)*QKV_LD + VOFF + hk*HD + d0 + tx];
  }
  __syncthreads();
  #pragma unroll
  for (int i = 0; i < 4; ++i) {
    const int dl = ty*4 + i;
    Vtb[((size_t)bk*HD + d0 + dl)*SEQ + s0 + tx] = tile[tx][dl];
  }
}

// ---------------- MFMA flash attention v10: v7 + balanced pairing + in-reg P ----
// Block = 4 waves (256 thr) = the 4 q-heads of one hk, ONE 32-row q-tile.
// K/V (64-key tile) staged once per hk (GQA reuse), single-buffered.
// (1) qt = y<32 ? 63-y : y-32: each CU's TWO co-resident blocks (round-robin
//     dispatch) get q-tiles summing to 63 -> per-CU work ~constant 34.5 steps
//     (v7's big+small pairing gave 17..48-step CUs -> 1.4x makespan loss).
// (2) P^T -> PV B-fragment built IN REGISTERS: from D-layout key=(r&3)+8*(r>>2)
//     +4*hi, the B-frag P[qrow=c][kc*16+hi*8+i] needs only a lane<->lane+32
//     exchange: pack2 pairs + __shfl_xor(32) + hi-select. Removes the per-step
//     16x ds_write + lgkmcnt(0) + 4x ds_read critical path and frees Pl:
//     LDS 48KB -> 32KB.
__global__ __launch_bounds__(256) void attn_mfma10(
    const ushort_t* __restrict__ Qb, const ushort_t* __restrict__ Kb,
    const ushort_t* __restrict__ Vtb, ushort_t* __restrict__ O)
{
  // [0,16384) Kl: 64 keys x 256B (swz ^((key&15)<<4))
  // [16384,32768) Vl: 128 dims x 128B (64 keys, swz ^((dim&7)<<4))
  __shared__ char smem[32768];

  const int bx = blockIdx.x;                // b*NKV + hk
  const int y  = blockIdx.y;
  const int qt = (y < 32) ? (63 - y) : (y - 32);
  const int b = bx >> 2, hk = bx & 3;
  const int t = threadIdx.x, w = t >> 6, lane = t & 63;
  const int c = lane & 31, hi = lane >> 5;
  const int h = hk*4 + w;                   // this wave's q-head
  const int qw0 = qt*32;
  const int qg  = qw0 + c;
  const int nsteps = (qt + 2) >> 1;         // ceil((qt+1)/2) 64-key tiles

  const char* Kbb = (const char*)(Kb + (size_t)(b*NKV + hk)*SEQ*HD);
  const char* Vbb = (const char*)(Vtb + (size_t)(b*NKV + hk)*HD*SEQ);
  char* klds = smem;
  char* vlds = smem + 16384;

  // staging offsets: 256 threads, 4 x 16B slots each per K and V tile
  int ksrc[4], vsrc[4], ldst[4];
  #pragma unroll
  for (int u = 0; u < 4; ++u) {
    const int idx = u*256 + t;
    const int krow = idx >> 4, kof = (idx & 15) << 4;   // K: 64 rows x 256B
    ksrc[u] = krow*256 + (kof ^ ((krow & 15) << 4));
    const int vd = idx >> 3,  vof = (idx & 7) << 4;     // V: 128 dim-rows x 128B
    vsrc[u] = vd*(SEQ*2) + (vof ^ ((vd & 7) << 4));
    ldst[u] = idx*16;
  }

  bf16x8 qf[8];
  {
    const ushort_t* qrow = Qb + (size_t)(b*SEQ + qg)*HIDDEN + h*HD;
    #pragma unroll
    for (int kc = 0; kc < 8; ++kc)
      qf[kc] = *(const bf16x8*)(qrow + kc*16 + hi*8);
  }

  f32x16 ot[4];
  #pragma unroll
  for (int nc = 0; nc < 4; ++nc)
    #pragma unroll
    for (int r = 0; r < 16; ++r) ot[nc][r] = 0.f;
  float m = -1e30f, l = 0.f;

  // stage tile 0
  #pragma unroll
  for (int u = 0; u < 4; ++u) {
    gload16(Kbb + ksrc[u], klds + ldst[u]);
    gload16(Vbb + vsrc[u], vlds + ldst[u]);
  }
  __syncthreads();   // vmcnt(0) drain + barrier

  for (int kt = 0; kt < nsteps; ++kt) {
    // ---- QK^T (swapped): D col = q-row, rows = keys
    f32x16 s[2];
    #pragma unroll
    for (int kn = 0; kn < 2; ++kn)
      #pragma unroll
      for (int r = 0; r < 16; ++r) s[kn][r] = 0.f;
    #pragma unroll
    for (int kn = 0; kn < 2; ++kn) {
      const int row = kn*32 + c;
      const int sw = (row & 15) << 4;
      #pragma unroll
      for (int kc = 0; kc < 8; ++kc) {
        const bf16x8 ka = *(const bf16x8*)(klds + row*256 + ((kc*32 + hi*16) ^ sw));
        s[kn] = __builtin_amdgcn_mfma_f32_32x32x16_bf16(ka, qf[kc], s[kn], 0, 0, 0);
      }
    }
    // ---- causal mask: only the last tile can cross the diagonal.
    if (kt == nsteps - 1) {
      #pragma unroll
      for (int kn = 0; kn < 2; ++kn)
        #pragma unroll
        for (int r = 0; r < 16; ++r) {
          const int kg_ = kt*64 + kn*32 + (r & 3) + 8*(r >> 2) + 4*hi;
          if (kg_ > qg) s[kn][r] = -1e30f;
        }
    }
    // ---- online softmax (exp2 domain, lane-local per q-row)
    float mx[16];
    #pragma unroll
    for (int r = 0; r < 16; ++r) mx[r] = fmaxf(s[0][r], s[1][r]);
    #pragma unroll
    for (int st = 8; st > 0; st >>= 1)
      #pragma unroll
      for (int r = 0; r < 8; ++r)
        if (r < st) mx[r] = fmaxf(mx[r], mx[r + st]);
    const float pm = fmaxf(mx[0], __shfl_xor(mx[0], 32));
    // T13 defer-max: skip O/l rescale while max growth <= 8 (P <= 2^8, fp32-safe)
    if (!__all(pm - m <= 8.f)) {
      const float mnew = fmaxf(m, pm);
      const float corr = exp2f(m - mnew);
      m = mnew;
      l *= corr;
      #pragma unroll
      for (int nc = 0; nc < 4; ++nc) ot[nc] *= corr;
    }
    float ls = 0.f;
    #pragma unroll
    for (int kn = 0; kn < 2; ++kn)
      #pragma unroll
      for (int r = 0; r < 16; ++r) {
        const float p = exp2f(s[kn][r] - m);
        ls += p;
        s[kn][r] = p;
      }
    l += ls;
    // ---- PV with in-register P B-fragments.
    // Lane (c,hi) owns P[qrow=c][key = kn*32 + (r&3) + 8*(r>>2) + 4*hi].
    // B-frag for k-chunk kc=kn*2+rem needs P[c][kn*32 + rem*16 + hi*8 + i]:
    //   hi=0: words {A0,A1} own (offs 0-3 of 8-block 2rem) + partner's {A0,A1}
    //         (its offs 4-7 of the same 8-block) via shfl_xor(32);
    //   hi=1: partner's {B0,B1} (offs 0-3 of 8-block 2rem+1) + own {B0,B1}.
    #pragma unroll
    for (int kn = 0; kn < 2; ++kn) {
      #pragma unroll
      for (int rem = 0; rem < 2; ++rem) {
        const int base = 8*rem;
        const unsigned A0 = pack2(s[kn][base+0], s[kn][base+1]);
        const unsigned A1 = pack2(s[kn][base+2], s[kn][base+3]);
        const unsigned B0 = pack2(s[kn][base+4], s[kn][base+5]);
        const unsigned B1 = pack2(s[kn][base+6], s[kn][base+7]);
        const unsigned u  = hi ? A0 : B0;
        const unsigned v  = hi ? A1 : B1;
        const unsigned su = (unsigned)__shfl_xor((int)u, 32);
        const unsigned sv = (unsigned)__shfl_xor((int)v, 32);
        uint4 wv;
        wv.x = hi ? su : A0;
        wv.y = hi ? sv : A1;
        wv.z = hi ? B0 : su;
        wv.w = hi ? B1 : sv;
        const bf16x8 pb = __builtin_bit_cast(bf16x8, wv);
        const int kc = kn*2 + rem;
        #pragma unroll
        for (int nc = 0; nc < 4; ++nc) {
          const int dim = nc*32 + c;
          const bf16x8 va = *(const bf16x8*)(vlds + dim*128 + ((kc*32 + hi*16) ^ ((dim & 7) << 4)));
          ot[nc] = __builtin_amdgcn_mfma_f32_32x32x16_bf16(va, pb, ot[nc], 0, 0, 0);
        }
      }
    }
    // ---- stage next tile (single buffer)
    if (kt < nsteps - 1) {
      __syncthreads();   // all waves done reading Kl/Vl
      const size_t kto = (size_t)(kt + 1) * 16384;   // 64 keys * 256B
      const int    vto = (kt + 1) * 128;             // 64 keys * 2B within V rows
      #pragma unroll
      for (int u = 0; u < 4; ++u) {
        gload16(Kbb + kto + ksrc[u], klds + ldst[u]);
        gload16(Vbb + vto + vsrc[u], vlds + ldst[u]);
      }
      __syncthreads();   // vmcnt(0) drain: staged data visible
    }
  }

  // ---- epilogue (per-wave; outputs disjoint)
  const float lt = l + __shfl_xor(l, 32);
  const float inv = 1.f / lt;
  ushort_t* orow = O + (size_t)(b*SEQ + qg) * HIDDEN + h*HD;
  #pragma unroll
  for (int nc = 0; nc < 4; ++nc)
    #pragma unroll
    for (int r = 0; r < 16; r += 2) {
      const int dim = nc*32 + (r & 3) + 8*(r >> 2) + 4*hi;
      *(unsigned*)(orow + dim) = pack2(ot[nc][r]*inv, ot[nc][r+1]*inv);
    }
}

extern "C" void kernel_launch(void* const* d_in, const int* in_sizes, int n_in,
                              void* d_out, int out_size, void* d_ws, size_t ws_size,
                              hipStream_t stream)
{
  (void)in_sizes; (void)n_in; (void)out_size; (void)ws_size;
  const float* H  = (const float*)d_in[0];
  const float* Wq = (const float*)d_in[1];
  const float* Wk = (const float*)d_in[2];
  const float* Wv = (const float*)d_in[3];
  const float* Wo = (const float*)d_in[4];
  float* out = (float*)d_out;

  char* ws = (char*)d_ws;
  ushort_t* QKVb = (ushort_t*)ws;                      // [4096][3072] bf16  25.2 MB
  ushort_t* Hb   = (ushort_t*)(ws + 25165824);         // [4096][2048] bf16  (dead after gemm -> Qb)
  ushort_t* Qb   = Hb;
  ushort_t* Wt   = (ushort_t*)(ws + 41943040);         // [3072][2048] bf16  (reused for Wo)
  ushort_t* Kb   = (ushort_t*)(ws + 54525952);         // [2*4][2048][128]
  ushort_t* Vtb  = (ushort_t*)(ws + 58720256);         // [2*4][128][2048]
  ushort_t* Oat  = (ushort_t*)(ws + 62914560);         // [4096][2048] bf16

  conv_f2b<<<4096, 256, 0, stream>>>(H, Hb, NTOK*HIDDEN/8);
  transpose_f2b<<<dim3(64, 64), 256, 0, stream>>>(Wq, Wt,                     2048, 2048);
  transpose_f2b<<<dim3(16, 64), 256, 0, stream>>>(Wk, Wt + (size_t)2048*2048, 2048, 512);
  transpose_f2b<<<dim3(16, 64), 256, 0, stream>>>(Wv, Wt + (size_t)2560*2048, 2048, 512);

  bt_gemm<true><<<dim3(QKV_LD/128, NTOK/128), 256, 0, stream>>>(Hb, Wt, QKVb, QKV_LD);

  const int rope_total = NTOK * (NH + NKV) * (HD/2);
  rope_conv<<<(rope_total + 255)/256, 256, 0, stream>>>(QKVb, Qb, Kb);
  vt_conv<<<dim3(SEQ/32, 32), 256, 0, stream>>>(QKVb, Vtb);

  attn_mfma10<<<dim3(8, 64), 256, 0, stream>>>(Qb, Kb, Vtb, Oat);

  transpose_f2b<<<dim3(64, 64), 256, 0, stream>>>(Wo, Wt, 2048, 2048);
  bt_gemm<false><<<dim3(HIDDEN/128, NTOK/128), 256, 0, stream>>>(Oat, Wt, out, HIDDEN);
}

// Round 14
// 238.249 us; speedup vs baseline: 1.1316x; 1.0770x over previous
//
#include <hip/hip_runtime.h>
#include <hip/hip_bf16.h>
#include <cstdint>
#include <cstddef>

#define HIDDEN   2048
#define NH       16
#define NKV      4
#define HD       128
#define SEQ      2048
#define BATCH    2
#define NTOK     (BATCH*SEQ)      // 4096
#define QKV_LD   3072             // Q(2048) | K(512) | V(512)
#define KOFF     2048
#define VOFF     2560
#define SM_SCALE 0.08838834764831845f   // 1/sqrt(128)
#define LOG2E    1.4426950408889634f

typedef __attribute__((ext_vector_type(8)))  short bf16x8;
typedef __attribute__((ext_vector_type(4)))  float f32x4v;
typedef __attribute__((ext_vector_type(16))) float f32x16;
typedef unsigned short ushort_t;

__device__ __forceinline__ unsigned short f2bf(float f) {
  return __builtin_bit_cast(unsigned short, __float2bfloat16(f));
}
__device__ __forceinline__ float bf2f(ushort_t u) {
  return __builtin_bit_cast(float, (unsigned)u << 16);
}
__device__ __forceinline__ unsigned pack2(float a, float b) {
  return (unsigned)f2bf(a) | ((unsigned)f2bf(b) << 16);
}

// async global->LDS, 16B/lane; LDS dest lane-linear, swizzle realized on the GLOBAL src.
__device__ __forceinline__ void gload16(const void* g, void* l) {
  __builtin_amdgcn_global_load_lds(
      (const __attribute__((address_space(1))) unsigned int*)g,
      (__attribute__((address_space(3))) unsigned int*)l, 16, 0, 0);
}

// ---------------- conversion kernels ----------------
__global__ __launch_bounds__(256) void conv_f2b(
    const float* __restrict__ in, ushort_t* __restrict__ out, int n8)
{
  const int i = blockIdx.x*256 + threadIdx.x;
  if (i >= n8) return;
  const float4 a = ((const float4*)in)[2*i];
  const float4 b = ((const float4*)in)[2*i + 1];
  uint4 r;
  r.x = pack2(a.x, a.y); r.y = pack2(a.z, a.w);
  r.z = pack2(b.x, b.y); r.w = pack2(b.z, b.w);
  ((uint4*)out)[i] = r;
}

// W[K][N] fp32 -> Wt[N][K] bf16
__global__ __launch_bounds__(256) void transpose_f2b(
    const float* __restrict__ W, ushort_t* __restrict__ Wt, int K, int N)
{
  __shared__ float tile[32][33];
  const int n0 = blockIdx.x*32, k0 = blockIdx.y*32;
  const int tx = threadIdx.x & 31, ty = threadIdx.x >> 5;
  #pragma unroll
  for (int i = 0; i < 4; ++i)
    tile[ty*4 + i][tx] = W[(size_t)(k0 + ty*4 + i)*N + n0 + tx];
  __syncthreads();
  #pragma unroll
  for (int i = 0; i < 4; ++i) {
    const int nl = ty*4 + i;
    Wt[(size_t)(n0 + nl)*K + k0 + tx] = f2bf(tile[tx][nl]);
  }
}

// ---------------- bf16 MFMA GEMM (m97 structure), templated output dtype --------
template<bool B16OUT>
__global__ __launch_bounds__(256) void bt_gemm(
    const ushort_t* __restrict__ A, const ushort_t* __restrict__ Bt,
    void* __restrict__ Cv, int ldc)
{
  __shared__ ushort_t As[128*64];
  __shared__ ushort_t Bs[128*64];
  const int t = threadIdx.x, lane = t & 63, w = t >> 6;
  const int bm = blockIdx.y*128, bn = blockIdx.x*128;
  const int wr = w >> 1, wc = w & 1;
  const int lr = lane & 15, lg = lane >> 4;

  f32x4v acc[4][4];
  #pragma unroll
  for (int fm = 0; fm < 4; ++fm)
    #pragma unroll
    for (int fn = 0; fn < 4; ++fn)
      #pragma unroll
      for (int r = 0; r < 4; ++r) acc[fm][fn][r] = 0.f;

  const char* Ab = (const char*)A;
  const char* Bb = (const char*)Bt;
  char* asb = (char*)As;
  char* bsb = (char*)Bs;

  for (int kt = 0; kt < HIDDEN*2; kt += 128) {
    __syncthreads();
    #pragma unroll
    for (int u = 0; u < 4; ++u) {
      const int idx = u*256 + t;
      const int row = idx >> 3;
      const int kb  = (idx & 7) * 16;
      const int skb = kb ^ ((row & 7) << 4);
      gload16(Ab + (size_t)(bm + row)*4096 + kt + skb, asb + idx*16);
      gload16(Bb + (size_t)(bn + row)*4096 + kt + skb, bsb + idx*16);
    }
    __syncthreads();
    #pragma unroll
    for (int kc = 0; kc < 2; ++kc) {
      bf16x8 af[4], bfr[4];
      #pragma unroll
      for (int f = 0; f < 4; ++f) {
        const int rm = wr*64 + f*16 + lr;
        af[f]  = *(const bf16x8*)(asb + rm*128 + ((kc*64 + lg*16) ^ ((rm & 7) << 4)));
        const int rn = wc*64 + f*16 + lr;
        bfr[f] = *(const bf16x8*)(bsb + rn*128 + ((kc*64 + lg*16) ^ ((rn & 7) << 4)));
      }
      #pragma unroll
      for (int fm = 0; fm < 4; ++fm)
        #pragma unroll
        for (int fn = 0; fn < 4; ++fn)
          acc[fm][fn] = __builtin_amdgcn_mfma_f32_16x16x32_bf16(af[fm], bfr[fn], acc[fm][fn], 0, 0, 0);
    }
  }

  #pragma unroll
  for (int fm = 0; fm < 4; ++fm) {
    const int m = bm + wr*64 + fm*16 + lg*4;
    #pragma unroll
    for (int fn = 0; fn < 4; ++fn) {
      const int n = bn + wc*64 + fn*16 + lr;
      #pragma unroll
      for (int r = 0; r < 4; ++r) {
        if constexpr (B16OUT)
          ((ushort_t*)Cv)[(size_t)(m + r)*ldc + n] = f2bf(acc[fm][fn][r]);
        else
          ((float*)Cv)[(size_t)(m + r)*ldc + n] = acc[fm][fn][r];
      }
    }
  }
}

// RoPE on bf16 QKV; writes Qo (SM_SCALE*LOG2E folded -> softmax in exp2 domain)
// and Ko[b,hk][s][d].
__global__ __launch_bounds__(256) void rope_conv(
    const ushort_t* __restrict__ QKVb, ushort_t* __restrict__ Qo,
    ushort_t* __restrict__ Ko)
{
  const int total = NTOK * (NH + NKV) * (HD/2);
  int idx = blockIdx.x * 256 + threadIdx.x;
  if (idx >= total) return;
  const int i   = idx & 63;
  int tmp = idx >> 6;
  const int hs  = tmp % (NH + NKV);
  const int tkn = tmp / (NH + NKV);
  const int s   = tkn & (SEQ - 1);
  const int b   = tkn >> 11;
  const float invf = expf(-(float)i * 0.14391156831212787f);
  float sn, cs;
  sincosf((float)s * invf, &sn, &cs);
  const size_t base = (size_t)tkn * QKV_LD + (hs < NH ? hs * HD : KOFF + (hs - NH) * HD);
  const float x0 = bf2f(QKVb[base + i]);
  const float x1 = bf2f(QKVb[base + i + 64]);
  const float y0 = x0 * cs - x1 * sn;
  const float y1 = x1 * cs + x0 * sn;
  if (hs < NH) {
    ushort_t* q = Qo + (size_t)tkn * HIDDEN + hs * HD;
    q[i]      = f2bf(y0 * (SM_SCALE * LOG2E));
    q[i + 64] = f2bf(y1 * (SM_SCALE * LOG2E));
  } else {
    ushort_t* k = Ko + ((size_t)(b*NKV + (hs - NH))*SEQ + s) * HD;
    k[i]      = f2bf(y0);
    k[i + 64] = f2bf(y1);
  }
}

// V columns of QKVb -> Vtb[b,hk][d][s]
__global__ __launch_bounds__(256) void vt_conv(
    const ushort_t* __restrict__ QKVb, ushort_t* __restrict__ Vtb)
{
  __shared__ ushort_t tile[32][33];
  const int s0 = blockIdx.x*32;
  const int d0 = (blockIdx.y & 3)*32;
  const int bk = blockIdx.y >> 2;
  const int b = bk >> 2, hk = bk & 3;
  const int tx = threadIdx.x & 31, ty = threadIdx.x >> 5;
  #pragma unroll
  for (int i = 0; i < 4; ++i) {
    const int sl = ty*4 + i;
    tile[sl][tx] = QKVb[(size_t)(b*SEQ + s0 + sl)*QKV_LD + VOFF + hk*HD + d0 + tx];
  }
  __syncthreads();
  #pragma unroll
  for (int i = 0; i < 4; ++i) {
    const int dl = ty*4 + i;
    Vtb[((size_t)bk*HD + d0 + dl)*SEQ + s0 + tx] = tile[tx][dl];
  }
}

// ---------------- MFMA flash attention v11: v7 + in-reg P + double-buffered K/V ----
// Block = 4 waves (256 thr) = the 4 q-heads of one hk, ONE 32-row q-tile.
// Dispatch = v7's (qt = 63 - y, big first): 2 similar-length blocks co-resident
// per CU (v13 taught: CONCURRENCY beats total-balance — complementary pairs
// leave the CU 1-block for most of the time).
// In-reg P (v10, verified bit-identical): no Pl LDS, conflicts 5.7M -> 2.2M.
// Double-buffer K/V (64 KB): next tile's global_load_lds issues BEFORE compute,
// so the end-of-step barrier drains ~2500-cycle-old loads (~free) instead of
// exposing the full stage latency every step (v7's single-buffer did).
// 64 KB x 2 blocks = 128 <= 160 KB: residency preserved (v9's 80 KB was not).
__global__ __launch_bounds__(256) void attn_mfma11(
    const ushort_t* __restrict__ Qb, const ushort_t* __restrict__ Kb,
    const ushort_t* __restrict__ Vtb, ushort_t* __restrict__ O)
{
  // [0,16384) Kl0 | [16384,32768) Kl1 : 64 keys x 256B (swz ^((key&15)<<4))
  // [32768,49152) Vl0 | [49152,65536) Vl1 : 128 dims x 128B (swz ^((dim&7)<<4))
  __shared__ char smem[65536];

  const int bx = blockIdx.x;                // b*NKV + hk
  const int qt = 63 - (int)blockIdx.y;      // big q-tiles dispatched first
  const int b = bx >> 2, hk = bx & 3;
  const int t = threadIdx.x, w = t >> 6, lane = t & 63;
  const int c = lane & 31, hi = lane >> 5;
  const int h = hk*4 + w;                   // this wave's q-head
  const int qw0 = qt*32;
  const int qg  = qw0 + c;
  const int nsteps = (qt + 2) >> 1;         // ceil((qt+1)/2) 64-key tiles

  const char* Kbb = (const char*)(Kb + (size_t)(b*NKV + hk)*SEQ*HD);
  const char* Vbb = (const char*)(Vtb + (size_t)(b*NKV + hk)*HD*SEQ);

  // staging offsets: 256 threads, 4 x 16B slots each per K and V tile
  int ksrc[4], vsrc[4], ldst[4];
  #pragma unroll
  for (int u = 0; u < 4; ++u) {
    const int idx = u*256 + t;
    const int krow = idx >> 4, kof = (idx & 15) << 4;   // K: 64 rows x 256B
    ksrc[u] = krow*256 + (kof ^ ((krow & 15) << 4));
    const int vd = idx >> 3,  vof = (idx & 7) << 4;     // V: 128 dim-rows x 128B
    vsrc[u] = vd*(SEQ*2) + (vof ^ ((vd & 7) << 4));
    ldst[u] = idx*16;
  }

  bf16x8 qf[8];
  {
    const ushort_t* qrow = Qb + (size_t)(b*SEQ + qg)*HIDDEN + h*HD;
    #pragma unroll
    for (int kc = 0; kc < 8; ++kc)
      qf[kc] = *(const bf16x8*)(qrow + kc*16 + hi*8);
  }

  f32x16 ot[4];
  #pragma unroll
  for (int nc = 0; nc < 4; ++nc)
    #pragma unroll
    for (int r = 0; r < 16; ++r) ot[nc][r] = 0.f;
  float m = -1e30f, l = 0.f;

  // prologue: stage tile 0 into buf 0
  #pragma unroll
  for (int u = 0; u < 4; ++u) {
    gload16(Kbb + ksrc[u], smem + ldst[u]);
    gload16(Vbb + vsrc[u], smem + 32768 + ldst[u]);
  }
  __syncthreads();   // vmcnt(0) drain + barrier

  int cur = 0;
  for (int kt = 0; kt < nsteps; ++kt) {
    // ---- issue next tile's loads into the other buffer BEFORE computing:
    // they land during this step's compute; the end-of-step barrier drain is ~free.
    if (kt + 1 < nsteps) {
      const int nb = cur ^ 1;
      const size_t kto = (size_t)(kt + 1) * 16384;   // 64 keys * 256B
      const int    vto = (kt + 1) * 128;             // 64 keys * 2B within V rows
      #pragma unroll
      for (int u = 0; u < 4; ++u) {
        gload16(Kbb + kto + ksrc[u], smem + nb*16384 + ldst[u]);
        gload16(Vbb + vto + vsrc[u], smem + 32768 + nb*16384 + ldst[u]);
      }
    }
    const char* klds = smem + cur*16384;
    const char* vlds = smem + 32768 + cur*16384;
    // ---- QK^T (swapped): D col = q-row, rows = keys
    f32x16 s[2];
    #pragma unroll
    for (int kn = 0; kn < 2; ++kn)
      #pragma unroll
      for (int r = 0; r < 16; ++r) s[kn][r] = 0.f;
    #pragma unroll
    for (int kn = 0; kn < 2; ++kn) {
      const int row = kn*32 + c;
      const int sw = (row & 15) << 4;
      #pragma unroll
      for (int kc = 0; kc < 8; ++kc) {
        const bf16x8 ka = *(const bf16x8*)(klds + row*256 + ((kc*32 + hi*16) ^ sw));
        s[kn] = __builtin_amdgcn_mfma_f32_32x32x16_bf16(ka, qf[kc], s[kn], 0, 0, 0);
      }
    }
    // ---- causal mask: only the last tile can cross the diagonal
    if (kt == nsteps - 1) {
      #pragma unroll
      for (int kn = 0; kn < 2; ++kn)
        #pragma unroll
        for (int r = 0; r < 16; ++r) {
          const int kg_ = kt*64 + kn*32 + (r & 3) + 8*(r >> 2) + 4*hi;
          if (kg_ > qg) s[kn][r] = -1e30f;
        }
    }
    // ---- online softmax (exp2 domain, lane-local per q-row)
    float mx[16];
    #pragma unroll
    for (int r = 0; r < 16; ++r) mx[r] = fmaxf(s[0][r], s[1][r]);
    #pragma unroll
    for (int st = 8; st > 0; st >>= 1)
      #pragma unroll
      for (int r = 0; r < 8; ++r)
        if (r < st) mx[r] = fmaxf(mx[r], mx[r + st]);
    const float pm = fmaxf(mx[0], __shfl_xor(mx[0], 32));
    // T13 defer-max: skip O/l rescale while max growth <= 8 (P <= 2^8, fp32-safe)
    if (!__all(pm - m <= 8.f)) {
      const float mnew = fmaxf(m, pm);
      const float corr = exp2f(m - mnew);
      m = mnew;
      l *= corr;
      #pragma unroll
      for (int nc = 0; nc < 4; ++nc) ot[nc] *= corr;
    }
    float ls = 0.f;
    #pragma unroll
    for (int kn = 0; kn < 2; ++kn)
      #pragma unroll
      for (int r = 0; r < 16; ++r) {
        const float p = exp2f(s[kn][r] - m);
        ls += p;
        s[kn][r] = p;
      }
    l += ls;
    // ---- PV with in-register P B-fragments (v10, verified).
    // Lane (c,hi) owns P[qrow=c][key = kn*32 + (r&3) + 8*(r>>2) + 4*hi];
    // B-frag needs P[c][kn*32 + rem*16 + hi*8 + i] -> pack2 + shfl_xor(32) + hi-select.
    #pragma unroll
    for (int kn = 0; kn < 2; ++kn) {
      #pragma unroll
      for (int rem = 0; rem < 2; ++rem) {
        const int base = 8*rem;
        const unsigned A0 = pack2(s[kn][base+0], s[kn][base+1]);
        const unsigned A1 = pack2(s[kn][base+2], s[kn][base+3]);
        const unsigned B0 = pack2(s[kn][base+4], s[kn][base+5]);
        const unsigned B1 = pack2(s[kn][base+6], s[kn][base+7]);
        const unsigned u  = hi ? A0 : B0;
        const unsigned v  = hi ? A1 : B1;
        const unsigned su = (unsigned)__shfl_xor((int)u, 32);
        const unsigned sv = (unsigned)__shfl_xor((int)v, 32);
        uint4 wv;
        wv.x = hi ? su : A0;
        wv.y = hi ? sv : A1;
        wv.z = hi ? B0 : su;
        wv.w = hi ? B1 : sv;
        const bf16x8 pb = __builtin_bit_cast(bf16x8, wv);
        const int kc = kn*2 + rem;
        #pragma unroll
        for (int nc = 0; nc < 4; ++nc) {
          const int dim = nc*32 + c;
          const bf16x8 va = *(const bf16x8*)(vlds + dim*128 + ((kc*32 + hi*16) ^ ((dim & 7) << 4)));
          ot[nc] = __builtin_amdgcn_mfma_f32_32x32x16_bf16(va, pb, ot[nc], 0, 0, 0);
        }
      }
    }
    // ---- end of step: next-tile loads (issued a full compute phase ago) drain
    // cheaply; all waves done with buf cur before overwrite
    __syncthreads();
    cur ^= 1;
  }

  // ---- epilogue (per-wave; outputs disjoint)
  const float lt = l + __shfl_xor(l, 32);
  const float inv = 1.f / lt;
  ushort_t* orow = O + (size_t)(b*SEQ + qg) * HIDDEN + h*HD;
  #pragma unroll
  for (int nc = 0; nc < 4; ++nc)
    #pragma unroll
    for (int r = 0; r < 16; r += 2) {
      const int dim = nc*32 + (r & 3) + 8*(r >> 2) + 4*hi;
      *(unsigned*)(orow + dim) = pack2(ot[nc][r]*inv, ot[nc][r+1]*inv);
    }
}

extern "C" void kernel_launch(void* const* d_in, const int* in_sizes, int n_in,
                              void* d_out, int out_size, void* d_ws, size_t ws_size,
                              hipStream_t stream)
{
  (void)in_sizes; (void)n_in; (void)out_size; (void)ws_size;
  const float* H  = (const float*)d_in[0];
  const float* Wq = (const float*)d_in[1];
  const float* Wk = (const float*)d_in[2];
  const float* Wv = (const float*)d_in[3];
  const float* Wo = (const float*)d_in[4];
  float* out = (float*)d_out;

  char* ws = (char*)d_ws;
  ushort_t* QKVb = (ushort_t*)ws;                      // [4096][3072] bf16  25.2 MB
  ushort_t* Hb   = (ushort_t*)(ws + 25165824);         // [4096][2048] bf16  (dead after gemm -> Qb)
  ushort_t* Qb   = Hb;
  ushort_t* Wt   = (ushort_t*)(ws + 41943040);         // [3072][2048] bf16  (reused for Wo)
  ushort_t* Kb   = (ushort_t*)(ws + 54525952);         // [2*4][2048][128]
  ushort_t* Vtb  = (ushort_t*)(ws + 58720256);         // [2*4][128][2048]
  ushort_t* Oat  = (ushort_t*)(ws + 62914560);         // [4096][2048] bf16

  conv_f2b<<<4096, 256, 0, stream>>>(H, Hb, NTOK*HIDDEN/8);
  transpose_f2b<<<dim3(64, 64), 256, 0, stream>>>(Wq, Wt,                     2048, 2048);
  transpose_f2b<<<dim3(16, 64), 256, 0, stream>>>(Wk, Wt + (size_t)2048*2048, 2048, 512);
  transpose_f2b<<<dim3(16, 64), 256, 0, stream>>>(Wv, Wt + (size_t)2560*2048, 2048, 512);

  bt_gemm<true><<<dim3(QKV_LD/128, NTOK/128), 256, 0, stream>>>(Hb, Wt, QKVb, QKV_LD);

  const int rope_total = NTOK * (NH + NKV) * (HD/2);
  rope_conv<<<(rope_total + 255)/256, 256, 0, stream>>>(QKVb, Qb, Kb);
  vt_conv<<<dim3(SEQ/32, 32), 256, 0, stream>>>(QKVb, Vtb);

  attn_mfma11<<<dim3(8, 64), 256, 0, stream>>>(Qb, Kb, Vtb, Oat);

  transpose_f2b<<<dim3(64, 64), 256, 0, stream>>>(Wo, Wt, 2048, 2048);
  bt_gemm<false><<<dim3(HIDDEN/128, NTOK/128), 256, 0, stream>>>(Oat, Wt, out, HIDDEN);
}

// Round 15
// 211.210 us; speedup vs baseline: 1.2765x; 1.1280x over previous
//
#include <hip/hip_runtime.h>
#include <hip/hip_bf16.h>
#include <cstdint>
#include <cstddef>

#define HIDDEN   2048
#define NH       16
#define NKV      4
#define HD       128
#define SEQ      2048
#define BATCH    2
#define NTOK     (BATCH*SEQ)      // 4096
#define QKV_LD   3072             // Q(2048) | K(512) | V(512)
#define KOFF     2048
#define VOFF     2560
#define SM_SCALE 0.08838834764831845f   // 1/sqrt(128)
#define LOG2E    1.4426950408889634f

typedef __attribute__((ext_vector_type(8)))  short bf16x8;
typedef __attribute__((ext_vector_type(4)))  float f32x4v;
typedef __attribute__((ext_vector_type(16))) float f32x16;
typedef unsigned short ushort_t;

__device__ __forceinline__ unsigned short f2bf(float f) {
  return __builtin_bit_cast(unsigned short, __float2bfloat16(f));
}
__device__ __forceinline__ float bf2f(ushort_t u) {
  return __builtin_bit_cast(float, (unsigned)u << 16);
}
__device__ __forceinline__ unsigned pack2(float a, float b) {
  return (unsigned)f2bf(a) | ((unsigned)f2bf(b) << 16);
}

// async global->LDS, 16B/lane; LDS dest lane-linear, swizzle realized on the GLOBAL src.
__device__ __forceinline__ void gload16(const void* g, void* l) {
  __builtin_amdgcn_global_load_lds(
      (const __attribute__((address_space(1))) unsigned int*)g,
      (__attribute__((address_space(3))) unsigned int*)l, 16, 0, 0);
}

// ---------------- conversion kernels ----------------
__global__ __launch_bounds__(256) void conv_f2b(
    const float* __restrict__ in, ushort_t* __restrict__ out, int n8)
{
  const int i = blockIdx.x*256 + threadIdx.x;
  if (i >= n8) return;
  const float4 a = ((const float4*)in)[2*i];
  const float4 b = ((const float4*)in)[2*i + 1];
  uint4 r;
  r.x = pack2(a.x, a.y); r.y = pack2(a.z, a.w);
  r.z = pack2(b.x, b.y); r.w = pack2(b.z, b.w);
  ((uint4*)out)[i] = r;
}

// W[K][N] fp32 -> Wt[N][K] bf16
__global__ __launch_bounds__(256) void transpose_f2b(
    const float* __restrict__ W, ushort_t* __restrict__ Wt, int K, int N)
{
  __shared__ float tile[32][33];
  const int n0 = blockIdx.x*32, k0 = blockIdx.y*32;
  const int tx = threadIdx.x & 31, ty = threadIdx.x >> 5;
  #pragma unroll
  for (int i = 0; i < 4; ++i)
    tile[ty*4 + i][tx] = W[(size_t)(k0 + ty*4 + i)*N + n0 + tx];
  __syncthreads();
  #pragma unroll
  for (int i = 0; i < 4; ++i) {
    const int nl = ty*4 + i;
    Wt[(size_t)(n0 + nl)*K + k0 + tx] = f2bf(tile[tx][nl]);
  }
}

// ---------------- bf16 MFMA GEMM v2: 256-row tile, 8 waves, dbuf issue-early ----
// C[M][N] = A[M][K=2048] @ Bt[N][K=2048]^T. BM=256, BN in {256,128}, BK=64.
// 512 thr = 8 waves as WM x WN grid (WN=BN/64): per-wave C = (256/WM) x 64.
// LDS = 2 buffers x (A 32KB + B BN*128B): 128KB (BN=256) / 96KB (BN=128).
// Pipeline: ALL next-tile global_load_lds issue at the START of tile t's body;
// the tile's 48 ds_read_b128 + 64 MFMA/wave (~1000 cyc) cover the latency, so
// the end-of-tile __syncthreads (implicit vmcnt(0)) drains already-landed loads
// -> no per-step exposed stage latency (the m97-structure stall).
// Swizzle ^((row&7)<<4) on BOTH global-src and ds_read (involution, rule #21);
// read pattern is bank-BALANCED (8 lanes on each of 8 bank-quads = min cycles).
template<int BN, bool B16OUT>
__global__ __launch_bounds__(512, 1) void bt_gemm2(
    const ushort_t* __restrict__ A, const ushort_t* __restrict__ Bt,
    void* __restrict__ Cv, int ldc)
{
  constexpr int WN = BN/64;            // waves in N: 4 or 2
  constexpr int WM = 8/WN;             // waves in M: 2 or 4
  constexpr int MF = 16/WM;            // M-frags per wave: 8 or 4
  constexpr int BROUNDS = BN/64;       // B staging rounds (512 thr x 16B each)
  constexpr int BUFB = 32768 + BN*128; // bytes per buffer (A tile + B tile)
  __shared__ char smem[2*BUFB];

  const int t = threadIdx.x, lane = t & 63, w = t >> 6;
  const int wm = w / WN, wn = w % WN;
  const int bm = blockIdx.y*256, bn = blockIdx.x*BN;
  const int lr = lane & 15, lg = lane >> 4;

  f32x4v acc[MF][4];
  #pragma unroll
  for (int mf = 0; mf < MF; ++mf)
    #pragma unroll
    for (int nf = 0; nf < 4; ++nf)
      #pragma unroll
      for (int r = 0; r < 4; ++r) acc[mf][nf][r] = 0.f;

  const char* Ab = (const char*)A;
  const char* Bb = (const char*)Bt;

  // burst-issue one K-tile's staging (A: 4 rounds, B: BROUNDS rounds) into buffer d
  auto stage = [&](int kt2, int d) {
    char* ab = smem + d*BUFB;
    char* bb = ab + 32768;
    const int ktb = kt2*128;           // byte offset along K
    #pragma unroll
    for (int u = 0; u < 4; ++u) {
      const int idx = u*512 + t;
      const int row = idx >> 3;
      const int kb  = ((idx & 7)*16) ^ ((row & 7) << 4);
      gload16(Ab + (size_t)(bm + row)*4096 + ktb + kb, ab + idx*16);
    }
    #pragma unroll
    for (int u = 0; u < BROUNDS; ++u) {
      const int idx = u*512 + t;
      const int row = idx >> 3;
      const int kb  = ((idx & 7)*16) ^ ((row & 7) << 4);
      gload16(Bb + (size_t)(bn + row)*4096 + ktb + kb, bb + idx*16);
    }
  };

  // prologue: stage tile 0 into buf 0
  stage(0, 0);
  __syncthreads();

#define PHASE(q) { \
    bf16x8 af0k0, af0k1, af1k0, af1k1; \
    { const int rm = wm*(MF*16) + (2*(q))*16 + lr; \
      const char* ap = asp + rm*128; \
      const int sw = (rm & 7) << 4; \
      af0k0 = *(const bf16x8*)(ap + ((lg*16) ^ sw)); \
      af0k1 = *(const bf16x8*)(ap + ((64 + lg*16) ^ sw)); } \
    { const int rm = wm*(MF*16) + (2*(q)+1)*16 + lr; \
      const char* ap = asp + rm*128; \
      const int sw = (rm & 7) << 4; \
      af1k0 = *(const bf16x8*)(ap + ((lg*16) ^ sw)); \
      af1k1 = *(const bf16x8*)(ap + ((64 + lg*16) ^ sw)); } \
    __builtin_amdgcn_s_setprio(1); \
    _Pragma("unroll") \
    for (int nf = 0; nf < 4; ++nf) { \
      acc[2*(q)][nf]   = __builtin_amdgcn_mfma_f32_16x16x32_bf16(af0k0, bfr[nf][0], acc[2*(q)][nf],   0,0,0); \
      acc[2*(q)][nf]   = __builtin_amdgcn_mfma_f32_16x16x32_bf16(af0k1, bfr[nf][1], acc[2*(q)][nf],   0,0,0); \
      acc[2*(q)+1][nf] = __builtin_amdgcn_mfma_f32_16x16x32_bf16(af1k0, bfr[nf][0], acc[2*(q)+1][nf], 0,0,0); \
      acc[2*(q)+1][nf] = __builtin_amdgcn_mfma_f32_16x16x32_bf16(af1k1, bfr[nf][1], acc[2*(q)+1][nf], 0,0,0); \
    } \
    __builtin_amdgcn_s_setprio(0); }

  int cur = 0;
  for (int kt = 0; kt < 32; ++kt) {
    // issue next tile's loads FIRST (into the other buffer) - they land under
    // this tile's compute
    if (kt < 31) stage(kt + 1, cur ^ 1);
    const char* asp = smem + cur*BUFB;
    const char* bsp = asp + 32768;
    // B fragments (held across phases): 4 N-frags x 2 k-chunks
    bf16x8 bfr[4][2];
    #pragma unroll
    for (int nf = 0; nf < 4; ++nf) {
      const int rn = wn*64 + nf*16 + lr;
      const char* bp = bsp + rn*128;
      const int sw = (rn & 7) << 4;
      bfr[nf][0] = *(const bf16x8*)(bp + ((lg*16) ^ sw));
      bfr[nf][1] = *(const bf16x8*)(bp + ((64 + lg*16) ^ sw));
    }
    PHASE(0)
    PHASE(1)
    if constexpr (MF == 8) {
      PHASE(2)
      PHASE(3)
    }
    // end of tile: implicit vmcnt(0)+lgkmcnt(0) here drains loads issued a full
    // tile-body ago (~covered); all waves done with buf cur before overwrite
    __syncthreads();
    cur ^= 1;
  }
#undef PHASE

  // ---- C write (m89 D-layout: row = +lg*4+r, col = +lr)
  #pragma unroll
  for (int mf = 0; mf < MF; ++mf) {
    const int m = bm + wm*(MF*16) + mf*16 + lg*4;
    #pragma unroll
    for (int nf = 0; nf < 4; ++nf) {
      const int n = bn + wn*64 + nf*16 + lr;
      #pragma unroll
      for (int r = 0; r < 4; ++r) {
        if constexpr (B16OUT)
          ((ushort_t*)Cv)[(size_t)(m + r)*ldc + n] = f2bf(acc[mf][nf][r]);
        else
          ((float*)Cv)[(size_t)(m + r)*ldc + n] = acc[mf][nf][r];
      }
    }
  }
}

// RoPE on bf16 QKV; writes Qo (SM_SCALE*LOG2E folded -> softmax in exp2 domain)
// and Ko[b,hk][s][d].
__global__ __launch_bounds__(256) void rope_conv(
    const ushort_t* __restrict__ QKVb, ushort_t* __restrict__ Qo,
    ushort_t* __restrict__ Ko)
{
  const int total = NTOK * (NH + NKV) * (HD/2);
  int idx = blockIdx.x * 256 + threadIdx.x;
  if (idx >= total) return;
  const int i   = idx & 63;
  int tmp = idx >> 6;
  const int hs  = tmp % (NH + NKV);
  const int tkn = tmp / (NH + NKV);
  const int s   = tkn & (SEQ - 1);
  const int b   = tkn >> 11;
  const float invf = expf(-(float)i * 0.14391156831212787f);
  float sn, cs;
  sincosf((float)s * invf, &sn, &cs);
  const size_t base = (size_t)tkn * QKV_LD + (hs < NH ? hs * HD : KOFF + (hs - NH) * HD);
  const float x0 = bf2f(QKVb[base + i]);
  const float x1 = bf2f(QKVb[base + i + 64]);
  const float y0 = x0 * cs - x1 * sn;
  const float y1 = x1 * cs + x0 * sn;
  if (hs < NH) {
    ushort_t* q = Qo + (size_t)tkn * HIDDEN + hs * HD;
    q[i]      = f2bf(y0 * (SM_SCALE * LOG2E));
    q[i + 64] = f2bf(y1 * (SM_SCALE * LOG2E));
  } else {
    ushort_t* k = Ko + ((size_t)(b*NKV + (hs - NH))*SEQ + s) * HD;
    k[i]      = f2bf(y0);
    k[i + 64] = f2bf(y1);
  }
}

// V columns of QKVb -> Vtb[b,hk][d][s]
__global__ __launch_bounds__(256) void vt_conv(
    const ushort_t* __restrict__ QKVb, ushort_t* __restrict__ Vtb)
{
  __shared__ ushort_t tile[32][33];
  const int s0 = blockIdx.x*32;
  const int d0 = (blockIdx.y & 3)*32;
  const int bk = blockIdx.y >> 2;
  const int b = bk >> 2, hk = bk & 3;
  const int tx = threadIdx.x & 31, ty = threadIdx.x >> 5;
  #pragma unroll
  for (int i = 0; i < 4; ++i) {
    const int sl = ty*4 + i;
    tile[sl][tx] = QKVb[(size_t)(b*SEQ + s0 + sl)*QKV_LD + VOFF + hk*HD + d0 + tx];
  }
  __syncthreads();
  #pragma unroll
  for (int i = 0; i < 4; ++i) {
    const int dl = ty*4 + i;
    Vtb[((size_t)bk*HD + d0 + dl)*SEQ + s0 + tx] = tile[tx][dl];
  }
}

// ---------------- MFMA flash attention v11 (R14 winner, unchanged) ----------
__global__ __launch_bounds__(256) void attn_mfma11(
    const ushort_t* __restrict__ Qb, const ushort_t* __restrict__ Kb,
    const ushort_t* __restrict__ Vtb, ushort_t* __restrict__ O)
{
  __shared__ char smem[65536];

  const int bx = blockIdx.x;                // b*NKV + hk
  const int qt = 63 - (int)blockIdx.y;      // big q-tiles dispatched first
  const int b = bx >> 2, hk = bx & 3;
  const int t = threadIdx.x, w = t >> 6, lane = t & 63;
  const int c = lane & 31, hi = lane >> 5;
  const int h = hk*4 + w;                   // this wave's q-head
  const int qw0 = qt*32;
  const int qg  = qw0 + c;
  const int nsteps = (qt + 2) >> 1;         // ceil((qt+1)/2) 64-key tiles

  const char* Kbb = (const char*)(Kb + (size_t)(b*NKV + hk)*SEQ*HD);
  const char* Vbb = (const char*)(Vtb + (size_t)(b*NKV + hk)*HD*SEQ);

  int ksrc[4], vsrc[4], ldst[4];
  #pragma unroll
  for (int u = 0; u < 4; ++u) {
    const int idx = u*256 + t;
    const int krow = idx >> 4, kof = (idx & 15) << 4;   // K: 64 rows x 256B
    ksrc[u] = krow*256 + (kof ^ ((krow & 15) << 4));
    const int vd = idx >> 3,  vof = (idx & 7) << 4;     // V: 128 dim-rows x 128B
    vsrc[u] = vd*(SEQ*2) + (vof ^ ((vd & 7) << 4));
    ldst[u] = idx*16;
  }

  bf16x8 qf[8];
  {
    const ushort_t* qrow = Qb + (size_t)(b*SEQ + qg)*HIDDEN + h*HD;
    #pragma unroll
    for (int kc = 0; kc < 8; ++kc)
      qf[kc] = *(const bf16x8*)(qrow + kc*16 + hi*8);
  }

  f32x16 ot[4];
  #pragma unroll
  for (int nc = 0; nc < 4; ++nc)
    #pragma unroll
    for (int r = 0; r < 16; ++r) ot[nc][r] = 0.f;
  float m = -1e30f, l = 0.f;

  #pragma unroll
  for (int u = 0; u < 4; ++u) {
    gload16(Kbb + ksrc[u], smem + ldst[u]);
    gload16(Vbb + vsrc[u], smem + 32768 + ldst[u]);
  }
  __syncthreads();

  int cur = 0;
  for (int kt = 0; kt < nsteps; ++kt) {
    if (kt + 1 < nsteps) {
      const int nb = cur ^ 1;
      const size_t kto = (size_t)(kt + 1) * 16384;
      const int    vto = (kt + 1) * 128;
      #pragma unroll
      for (int u = 0; u < 4; ++u) {
        gload16(Kbb + kto + ksrc[u], smem + nb*16384 + ldst[u]);
        gload16(Vbb + vto + vsrc[u], smem + 32768 + nb*16384 + ldst[u]);
      }
    }
    const char* klds = smem + cur*16384;
    const char* vlds = smem + 32768 + cur*16384;
    f32x16 s[2];
    #pragma unroll
    for (int kn = 0; kn < 2; ++kn)
      #pragma unroll
      for (int r = 0; r < 16; ++r) s[kn][r] = 0.f;
    #pragma unroll
    for (int kn = 0; kn < 2; ++kn) {
      const int row = kn*32 + c;
      const int sw = (row & 15) << 4;
      #pragma unroll
      for (int kc = 0; kc < 8; ++kc) {
        const bf16x8 ka = *(const bf16x8*)(klds + row*256 + ((kc*32 + hi*16) ^ sw));
        s[kn] = __builtin_amdgcn_mfma_f32_32x32x16_bf16(ka, qf[kc], s[kn], 0, 0, 0);
      }
    }
    if (kt == nsteps - 1) {
      #pragma unroll
      for (int kn = 0; kn < 2; ++kn)
        #pragma unroll
        for (int r = 0; r < 16; ++r) {
          const int kg_ = kt*64 + kn*32 + (r & 3) + 8*(r >> 2) + 4*hi;
          if (kg_ > qg) s[kn][r] = -1e30f;
        }
    }
    float mx[16];
    #pragma unroll
    for (int r = 0; r < 16; ++r) mx[r] = fmaxf(s[0][r], s[1][r]);
    #pragma unroll
    for (int st = 8; st > 0; st >>= 1)
      #pragma unroll
      for (int r = 0; r < 8; ++r)
        if (r < st) mx[r] = fmaxf(mx[r], mx[r + st]);
    const float pm = fmaxf(mx[0], __shfl_xor(mx[0], 32));
    if (!__all(pm - m <= 8.f)) {
      const float mnew = fmaxf(m, pm);
      const float corr = exp2f(m - mnew);
      m = mnew;
      l *= corr;
      #pragma unroll
      for (int nc = 0; nc < 4; ++nc) ot[nc] *= corr;
    }
    float ls = 0.f;
    #pragma unroll
    for (int kn = 0; kn < 2; ++kn)
      #pragma unroll
      for (int r = 0; r < 16; ++r) {
        const float p = exp2f(s[kn][r] - m);
        ls += p;
        s[kn][r] = p;
      }
    l += ls;
    #pragma unroll
    for (int kn = 0; kn < 2; ++kn) {
      #pragma unroll
      for (int rem = 0; rem < 2; ++rem) {
        const int base = 8*rem;
        const unsigned A0 = pack2(s[kn][base+0], s[kn][base+1]);
        const unsigned A1 = pack2(s[kn][base+2], s[kn][base+3]);
        const unsigned B0 = pack2(s[kn][base+4], s[kn][base+5]);
        const unsigned B1 = pack2(s[kn][base+6], s[kn][base+7]);
        const unsigned u  = hi ? A0 : B0;
        const unsigned v  = hi ? A1 : B1;
        const unsigned su = (unsigned)__shfl_xor((int)u, 32);
        const unsigned sv = (unsigned)__shfl_xor((int)v, 32);
        uint4 wv;
        wv.x = hi ? su : A0;
        wv.y = hi ? sv : A1;
        wv.z = hi ? B0 : su;
        wv.w = hi ? B1 : sv;
        const bf16x8 pb = __builtin_bit_cast(bf16x8, wv);
        const int kc = kn*2 + rem;
        #pragma unroll
        for (int nc = 0; nc < 4; ++nc) {
          const int dim = nc*32 + c;
          const bf16x8 va = *(const bf16x8*)(vlds + dim*128 + ((kc*32 + hi*16) ^ ((dim & 7) << 4)));
          ot[nc] = __builtin_amdgcn_mfma_f32_32x32x16_bf16(va, pb, ot[nc], 0, 0, 0);
        }
      }
    }
    __syncthreads();
    cur ^= 1;
  }

  const float lt = l + __shfl_xor(l, 32);
  const float inv = 1.f / lt;
  ushort_t* orow = O + (size_t)(b*SEQ + qg) * HIDDEN + h*HD;
  #pragma unroll
  for (int nc = 0; nc < 4; ++nc)
    #pragma unroll
    for (int r = 0; r < 16; r += 2) {
      const int dim = nc*32 + (r & 3) + 8*(r >> 2) + 4*hi;
      *(unsigned*)(orow + dim) = pack2(ot[nc][r]*inv, ot[nc][r+1]*inv);
    }
}

extern "C" void kernel_launch(void* const* d_in, const int* in_sizes, int n_in,
                              void* d_out, int out_size, void* d_ws, size_t ws_size,
                              hipStream_t stream)
{
  (void)in_sizes; (void)n_in; (void)out_size; (void)ws_size;
  const float* H  = (const float*)d_in[0];
  const float* Wq = (const float*)d_in[1];
  const float* Wk = (const float*)d_in[2];
  const float* Wv = (const float*)d_in[3];
  const float* Wo = (const float*)d_in[4];
  float* out = (float*)d_out;

  char* ws = (char*)d_ws;
  ushort_t* QKVb = (ushort_t*)ws;                      // [4096][3072] bf16  25.2 MB
  ushort_t* Hb   = (ushort_t*)(ws + 25165824);         // [4096][2048] bf16  (dead after gemm -> Qb)
  ushort_t* Qb   = Hb;
  ushort_t* Wt   = (ushort_t*)(ws + 41943040);         // [3072][2048] bf16  (reused for Wo)
  ushort_t* Kb   = (ushort_t*)(ws + 54525952);         // [2*4][2048][128]
  ushort_t* Vtb  = (ushort_t*)(ws + 58720256);         // [2*4][128][2048]
  ushort_t* Oat  = (ushort_t*)(ws + 62914560);         // [4096][2048] bf16

  conv_f2b<<<4096, 256, 0, stream>>>(H, Hb, NTOK*HIDDEN/8);
  transpose_f2b<<<dim3(64, 64), 256, 0, stream>>>(Wq, Wt,                     2048, 2048);
  transpose_f2b<<<dim3(16, 64), 256, 0, stream>>>(Wk, Wt + (size_t)2048*2048, 2048, 512);
  transpose_f2b<<<dim3(16, 64), 256, 0, stream>>>(Wv, Wt + (size_t)2560*2048, 2048, 512);

  bt_gemm2<256, true><<<dim3(QKV_LD/256, NTOK/256), 512, 0, stream>>>(Hb, Wt, QKVb, QKV_LD);

  const int rope_total = NTOK * (NH + NKV) * (HD/2);
  rope_conv<<<(rope_total + 255)/256, 256, 0, stream>>>(QKVb, Qb, Kb);
  vt_conv<<<dim3(SEQ/32, 32), 256, 0, stream>>>(QKVb, Vtb);

  attn_mfma11<<<dim3(8, 64), 256, 0, stream>>>(Qb, Kb, Vtb, Oat);

  transpose_f2b<<<dim3(64, 64), 256, 0, stream>>>(Wo, Wt, 2048, 2048);
  bt_gemm2<128, false><<<dim3(HIDDEN/128, NTOK/256), 512, 0, stream>>>(Oat, Wt, out, HIDDEN);
}